// Round 5
// baseline (730.337 us; speedup 1.0000x reference)
//
#include <hip/hip_runtime.h>

// ---------------------------------------------------------------------------
// 3-layer GCN, CSR-gather formulation.
// GEMM writes only HW; gather computes agg = hw[g]*dis^2 + bias + sum(...)
// ---------------------------------------------------------------------------

__global__ __launch_bounds__(256) void k_count(const int* __restrict__ dst,
                                               int* __restrict__ cnt, int nE) {
    int e = blockIdx.x * 256 + threadIdx.x;
    if (e < nE) atomicAdd(&cnt[dst[e]], 1);
}

__global__ __launch_bounds__(256) void k_rsqrt(const int* __restrict__ cnt,
                                               float* __restrict__ dis, int nN) {
    int i = blockIdx.x * 256 + threadIdx.x;
    if (i < nN) dis[i] = rsqrtf((float)cnt[i] + 1.0f);
}

// hierarchical scan, stage 1: per-block (256-wide) exclusive scan + block sum
__global__ __launch_bounds__(256) void k_scan_blk(const int* __restrict__ cnt,
                                                  int* __restrict__ excl,
                                                  int* __restrict__ blk_sum, int nN) {
    __shared__ int sm[256];
    const int t = threadIdx.x;
    int i = blockIdx.x * 256 + t;
    int v = (i < nN) ? cnt[i] : 0;
    sm[t] = v;
    __syncthreads();
#pragma unroll
    for (int off = 1; off < 256; off <<= 1) {
        int x = (t >= off) ? sm[t - off] : 0;
        __syncthreads();
        sm[t] += x;
        __syncthreads();
    }
    if (i < nN) excl[i] = sm[t] - v;
    if (t == 255) blk_sum[blockIdx.x] = sm[255];
}

// stage 2: single small block scans the block sums (nB <= 256)
__global__ __launch_bounds__(256) void k_scan_top(int* __restrict__ blk_sum, int nB) {
    __shared__ int sm[256];
    const int t = threadIdx.x;
    int v = (t < nB) ? blk_sum[t] : 0;
    sm[t] = v;
    __syncthreads();
#pragma unroll
    for (int off = 1; off < 256; off <<= 1) {
        int x = (t >= off) ? sm[t - off] : 0;
        __syncthreads();
        sm[t] += x;
        __syncthreads();
    }
    if (t < nB) blk_sum[t] = sm[t] - v;   // exclusive offsets in place
    if (t == 0) blk_sum[nB] = sm[255];    // grand total
}

// stage 3: add block offsets -> row_ptr + cursor copy
__global__ __launch_bounds__(256) void k_scan_add(const int* __restrict__ excl,
                                                  const int* __restrict__ blk_sum,
                                                  int* __restrict__ row_ptr,
                                                  int* __restrict__ cursor,
                                                  int nN, int nB) {
    int i = blockIdx.x * 256 + threadIdx.x;
    if (i < nN) {
        int v = excl[i] + blk_sum[i >> 8];
        row_ptr[i] = v;
        cursor[i] = v;
    }
    if (i == 0) row_ptr[nN] = blk_sum[nB];
}

__global__ __launch_bounds__(256) void k_bin(const int* __restrict__ src,
                                             const int* __restrict__ dst,
                                             const float* __restrict__ dis,
                                             int* __restrict__ cursor,
                                             int* __restrict__ src_csr,
                                             float* __restrict__ norm_csr, int nE) {
    int e = blockIdx.x * 256 + threadIdx.x;
    if (e >= nE) return;
    int s = src[e], d = dst[e];
    int pos = atomicAdd(&cursor[d], 1);
    src_csr[pos] = s;
    norm_csr[pos] = dis[s] * dis[d];
}

// HW = (relu?(X)) @ W   [nrows x 128] @ [128 x 128]
// __launch_bounds__(256,3): VGPR cap 170 (need ~168) -> 3 waves/SIMD, no spill.
// LDS 48KB -> 3 blocks/CU. Round-4 lesson: (256,4) forced VGPR=64 -> 700MB of
// scratch spills. The minimal bound is the right one.
__global__ __launch_bounds__(256, 3) void k_gemm128(const float* __restrict__ X,
                                                    const float* __restrict__ W,
                                                    float* __restrict__ HW,
                                                    int nrows, int relu_in) {
    __shared__ float xs[64 * 128];   // 32 KB: X tile [64 rows][128 k]
    __shared__ float wsm[32 * 128];  // 16 KB: W chunk [32 k][128 cols]
    const int t = threadIdx.x;
    const int row0 = blockIdx.x * 64;
    const int tr = t >> 5;   // 0..7  -> 8 rows each
    const int tc = t & 31;   // 0..31 -> 4 cols each

    float acc[8][4];
#pragma unroll
    for (int i = 0; i < 8; ++i)
#pragma unroll
        for (int c = 0; c < 4; ++c) acc[i][c] = 0.f;

    // stage X tile: 2048 float4, 8 per thread, coalesced
#pragma unroll
    for (int i = 0; i < 8; ++i) {
        int f = t + i * 256;
        int r = f >> 5, k4 = f & 31;
        int gr = row0 + r;
        float4 v = make_float4(0.f, 0.f, 0.f, 0.f);
        if (gr < nrows) v = ((const float4*)X)[(size_t)gr * 32 + k4];
        if (relu_in) {
            v.x = fmaxf(v.x, 0.f); v.y = fmaxf(v.y, 0.f);
            v.z = fmaxf(v.z, 0.f); v.w = fmaxf(v.w, 0.f);
        }
        ((float4*)xs)[f] = v;
    }

    for (int kk = 0; kk < 128; kk += 32) {
        // stage W rows kk..kk+31 (1024 float4, 4 per thread)
#pragma unroll
        for (int i = 0; i < 4; ++i) {
            int f = t + i * 256;
            ((float4*)wsm)[f] = ((const float4*)W)[kk * 32 + f];
        }
        __syncthreads();
#pragma unroll
        for (int k4 = 0; k4 < 8; ++k4) {
            float4 b0 = *(const float4*)&wsm[(k4 * 4 + 0) * 128 + tc * 4];
            float4 b1 = *(const float4*)&wsm[(k4 * 4 + 1) * 128 + tc * 4];
            float4 b2 = *(const float4*)&wsm[(k4 * 4 + 2) * 128 + tc * 4];
            float4 b3 = *(const float4*)&wsm[(k4 * 4 + 3) * 128 + tc * 4];
#pragma unroll
            for (int i = 0; i < 8; ++i) {
                float4 a = *(const float4*)&xs[(tr * 8 + i) * 128 + kk + k4 * 4];
                acc[i][0] += a.x * b0.x + a.y * b1.x + a.z * b2.x + a.w * b3.x;
                acc[i][1] += a.x * b0.y + a.y * b1.y + a.z * b2.y + a.w * b3.y;
                acc[i][2] += a.x * b0.z + a.y * b1.z + a.z * b2.z + a.w * b3.z;
                acc[i][3] += a.x * b0.w + a.y * b1.w + a.z * b2.w + a.w * b3.w;
            }
        }
        __syncthreads();
    }

#pragma unroll
    for (int i = 0; i < 8; ++i) {
        int gr = row0 + tr * 8 + i;
        if (gr < nrows)
            ((float4*)HW)[(size_t)gr * 32 + tc] =
                make_float4(acc[i][0], acc[i][1], acc[i][2], acc[i][3]);
    }
}

// pull-aggregation: 32 threads per node, float4 per thread, register acc.
// acc init = hw[g]*dis[g]^2 + bias (self-loop folded in). Single write/elem.
__global__ __launch_bounds__(256) void k_gather(const float* __restrict__ HW,
                                                const int* __restrict__ row_ptr,
                                                const int* __restrict__ src_csr,
                                                const float* __restrict__ norm_csr,
                                                const float* __restrict__ dis,
                                                const float* __restrict__ bias,
                                                float* __restrict__ AGG, int nN) {
    int g = blockIdx.x * 8 + (threadIdx.x >> 5);
    if (g >= nN) return;
    int f4 = threadIdx.x & 31;
    int beg = row_ptr[g], end = row_ptr[g + 1];
    float dn = dis[g];
    float sn = dn * dn;
    float4 bv = ((const float4*)bias)[f4];
    float4 sv = ((const float4*)HW)[(size_t)g * 32 + f4];
    float4 acc = make_float4(sv.x * sn + bv.x, sv.y * sn + bv.y,
                             sv.z * sn + bv.z, sv.w * sn + bv.w);
    int e = beg;
    for (; e + 3 < end; e += 4) {  // 4-way unroll for memory-level parallelism
        int s0 = src_csr[e], s1 = src_csr[e + 1];
        int s2 = src_csr[e + 2], s3 = src_csr[e + 3];
        float n0 = norm_csr[e], n1 = norm_csr[e + 1];
        float n2 = norm_csr[e + 2], n3 = norm_csr[e + 3];
        float4 v0 = ((const float4*)HW)[(size_t)s0 * 32 + f4];
        float4 v1 = ((const float4*)HW)[(size_t)s1 * 32 + f4];
        float4 v2 = ((const float4*)HW)[(size_t)s2 * 32 + f4];
        float4 v3 = ((const float4*)HW)[(size_t)s3 * 32 + f4];
        acc.x += v0.x * n0 + v1.x * n1 + v2.x * n2 + v3.x * n3;
        acc.y += v0.y * n0 + v1.y * n1 + v2.y * n2 + v3.y * n3;
        acc.z += v0.z * n0 + v1.z * n1 + v2.z * n2 + v3.z * n3;
        acc.w += v0.w * n0 + v1.w * n1 + v2.w * n2 + v3.w * n3;
    }
    for (; e < end; ++e) {
        int s = src_csr[e];
        float nv = norm_csr[e];
        float4 v = ((const float4*)HW)[(size_t)s * 32 + f4];
        acc.x += v.x * nv; acc.y += v.y * nv;
        acc.z += v.z * nv; acc.w += v.w * nv;
    }
    ((float4*)AGG)[(size_t)g * 32 + f4] = acc;
}

// layer 3: hw3[n] = dot(relu(h2[n,:]), W3)
__global__ __launch_bounds__(256) void k_gemv(const float* __restrict__ H,
                                              const float* __restrict__ W3,
                                              float* __restrict__ hw3, int nN) {
    int wid = (blockIdx.x * 256 + threadIdx.x) >> 6;
    int lane = threadIdx.x & 63;
    if (wid >= nN) return;
    float v0 = fmaxf(H[(size_t)wid * 128 + lane], 0.f);
    float v1 = fmaxf(H[(size_t)wid * 128 + 64 + lane], 0.f);
    float sum = v0 * W3[lane] + v1 * W3[64 + lane];
#pragma unroll
    for (int off = 32; off > 0; off >>= 1) sum += __shfl_down(sum, off);
    if (lane == 0) hw3[wid] = sum;
}

// scalar pull-aggregation + self-loop + bias + final relu -> d_out
__global__ __launch_bounds__(256) void k_gather3(const float* __restrict__ hw3,
                                                 const int* __restrict__ row_ptr,
                                                 const int* __restrict__ src_csr,
                                                 const float* __restrict__ norm_csr,
                                                 const float* __restrict__ dis,
                                                 const float* __restrict__ b3,
                                                 float* __restrict__ out, int nN) {
    int i = blockIdx.x * 256 + threadIdx.x;
    if (i >= nN) return;
    float dn = dis[i];
    float acc = hw3[i] * dn * dn + b3[0];
    int beg = row_ptr[i], end = row_ptr[i + 1];
    for (int e = beg; e < end; ++e) acc += hw3[src_csr[e]] * norm_csr[e];
    out[i] = fmaxf(acc, 0.f);
}

extern "C" void kernel_launch(void* const* d_in, const int* in_sizes, int n_in,
                              void* d_out, int out_size, void* d_ws, size_t ws_size,
                              hipStream_t stream) {
    const float* x  = (const float*)d_in[0];
    const int*   ei = (const int*)d_in[1];
    const float* W1 = (const float*)d_in[2];
    const float* b1 = (const float*)d_in[3];
    const float* W2 = (const float*)d_in[4];
    const float* b2 = (const float*)d_in[5];
    const float* W3 = (const float*)d_in[6];
    const float* b3 = (const float*)d_in[7];

    const int nN = in_sizes[0] / 128;
    const int nE = in_sizes[1] / 2;
    const int* src = ei;
    const int* dst = ei + nE;

    const int nB = (nN + 255) / 256;   // scan blocks

    // workspace layout
    char* p = (char*)d_ws;
    int*   cnt      = (int*)p;            p += (size_t)nN * 4;
    int*   cursor   = (int*)p;            p += (size_t)nN * 4;
    int*   excl     = (int*)p;            p += (size_t)nN * 4;
    int*   blk_sum  = (int*)p;            p += (size_t)(nB + 1) * 4;
    int*   row_ptr  = (int*)p;            p += (size_t)(nN + 1) * 4;
    int*   src_csr  = (int*)p;            p += (size_t)nE * 4;
    float* norm_csr = (float*)p;          p += (size_t)nE * 4;
    float* dis      = (float*)p;          p += (size_t)nN * 4;
    float* bufA     = (float*)p;          p += (size_t)nN * 128 * 4;  // hw
    float* bufB     = (float*)p;          p += (size_t)nN * 128 * 4;  // h / agg
    float* hw3      = bufA;               // bufA free by the time gemv runs

    const int BE  = (nE + 255) / 256;
    const int BN  = (nN + 255) / 256;
    const int BG  = (nN + 63) / 64;
    const int BGA = (nN + 7) / 8;
    const int BGV = (nN + 3) / 4;

    // --- CSR build + norm precompute ---
    hipMemsetAsync(cnt, 0, (size_t)nN * sizeof(int), stream);
    k_count   <<<BE, 256, 0, stream>>>(dst, cnt, nE);
    k_rsqrt   <<<BN, 256, 0, stream>>>(cnt, dis, nN);
    k_scan_blk<<<nB, 256, 0, stream>>>(cnt, excl, blk_sum, nN);
    k_scan_top<<<1, 256, 0, stream>>>(blk_sum, nB);
    k_scan_add<<<nB, 256, 0, stream>>>(excl, blk_sum, row_ptr, cursor, nN, nB);
    k_bin     <<<BE, 256, 0, stream>>>(src, dst, dis, cursor, src_csr, norm_csr, nE);

    // --- layer 1: x -> bufB ---
    k_gemm128<<<BG, 256, 0, stream>>>(x, W1, bufA, nN, 0);
    k_gather <<<BGA, 256, 0, stream>>>(bufA, row_ptr, src_csr, norm_csr, dis, b1, bufB, nN);

    // --- layer 2: relu(bufB) -> bufB ---
    k_gemm128<<<BG, 256, 0, stream>>>(bufB, W2, bufA, nN, 1);
    k_gather <<<BGA, 256, 0, stream>>>(bufA, row_ptr, src_csr, norm_csr, dis, b2, bufB, nN);

    // --- layer 3: relu(bufB) -> d_out ---
    k_gemv   <<<BGV, 256, 0, stream>>>(bufB, W3, hw3, nN);
    k_gather3<<<BN, 256, 0, stream>>>(hw3, row_ptr, src_csr, norm_csr, dis, b3,
                                      (float*)d_out, nN);
}

// Round 6
// 343.449 us; speedup vs baseline: 2.1265x; 2.1265x over previous
//
#include <hip/hip_runtime.h>

// ---------------------------------------------------------------------------
// 3-layer GCN, CSR-gather formulation.
// GEMM: X tile in LDS (32KB), W read directly from global (L2-resident 64KB).
// Lesson R4/R5: __launch_bounds__ min-waves arg caps VGPR at 256/w -> spills.
// Never force it here; occupancy comes from the small LDS footprint instead.
// ---------------------------------------------------------------------------

__global__ __launch_bounds__(256) void k_count(const int* __restrict__ dst,
                                               int* __restrict__ cnt, int nE) {
    int e = blockIdx.x * 256 + threadIdx.x;
    if (e < nE) atomicAdd(&cnt[dst[e]], 1);
}

__global__ __launch_bounds__(256) void k_rsqrt(const int* __restrict__ cnt,
                                               float* __restrict__ dis, int nN) {
    int i = blockIdx.x * 256 + threadIdx.x;
    if (i < nN) dis[i] = rsqrtf((float)cnt[i] + 1.0f);
}

// hierarchical scan, stage 1: per-block (256-wide) exclusive scan + block sum
__global__ __launch_bounds__(256) void k_scan_blk(const int* __restrict__ cnt,
                                                  int* __restrict__ excl,
                                                  int* __restrict__ blk_sum, int nN) {
    __shared__ int sm[256];
    const int t = threadIdx.x;
    int i = blockIdx.x * 256 + t;
    int v = (i < nN) ? cnt[i] : 0;
    sm[t] = v;
    __syncthreads();
#pragma unroll
    for (int off = 1; off < 256; off <<= 1) {
        int x = (t >= off) ? sm[t - off] : 0;
        __syncthreads();
        sm[t] += x;
        __syncthreads();
    }
    if (i < nN) excl[i] = sm[t] - v;
    if (t == 255) blk_sum[blockIdx.x] = sm[255];
}

// stage 2: single small block scans the block sums (nB <= 256)
__global__ __launch_bounds__(256) void k_scan_top(int* __restrict__ blk_sum, int nB) {
    __shared__ int sm[256];
    const int t = threadIdx.x;
    int v = (t < nB) ? blk_sum[t] : 0;
    sm[t] = v;
    __syncthreads();
#pragma unroll
    for (int off = 1; off < 256; off <<= 1) {
        int x = (t >= off) ? sm[t - off] : 0;
        __syncthreads();
        sm[t] += x;
        __syncthreads();
    }
    if (t < nB) blk_sum[t] = sm[t] - v;   // exclusive offsets in place
    if (t == 0) blk_sum[nB] = sm[255];    // grand total
}

// stage 3: add block offsets -> row_ptr + cursor copy
__global__ __launch_bounds__(256) void k_scan_add(const int* __restrict__ excl,
                                                  const int* __restrict__ blk_sum,
                                                  int* __restrict__ row_ptr,
                                                  int* __restrict__ cursor,
                                                  int nN, int nB) {
    int i = blockIdx.x * 256 + threadIdx.x;
    if (i < nN) {
        int v = excl[i] + blk_sum[i >> 8];
        row_ptr[i] = v;
        cursor[i] = v;
    }
    if (i == 0) row_ptr[nN] = blk_sum[nB];
}

__global__ __launch_bounds__(256) void k_bin(const int* __restrict__ src,
                                             const int* __restrict__ dst,
                                             const float* __restrict__ dis,
                                             int* __restrict__ cursor,
                                             int* __restrict__ src_csr,
                                             float* __restrict__ norm_csr, int nE) {
    int e = blockIdx.x * 256 + threadIdx.x;
    if (e >= nE) return;
    int s = src[e], d = dst[e];
    int pos = atomicAdd(&cursor[d], 1);
    src_csr[pos] = s;
    norm_csr[pos] = dis[s] * dis[d];
}

// HW = (relu?(X)) @ W   [nrows x 128] @ [128 x 128]
// X tile (64 rows) in LDS; W fragments loaded straight from global (L2-hot,
// broadcast across half-waves). One barrier total; 32KB LDS -> 5 blocks/CU.
__global__ __launch_bounds__(256) void k_gemm128(const float* __restrict__ X,
                                                 const float* __restrict__ W,
                                                 float* __restrict__ HW,
                                                 int nrows, int relu_in) {
    __shared__ float xs[64 * 128];   // 32 KB: X tile [64 rows][128 k]
    const int t = threadIdx.x;
    const int row0 = blockIdx.x * 64;
    const int tr = t >> 5;   // 0..7  -> 8 rows each
    const int tc = t & 31;   // 0..31 -> 4 cols each

    float acc[8][4];
#pragma unroll
    for (int i = 0; i < 8; ++i)
#pragma unroll
        for (int c = 0; c < 4; ++c) acc[i][c] = 0.f;

    // stage X tile: 2048 float4, 8 per thread, coalesced
#pragma unroll
    for (int i = 0; i < 8; ++i) {
        int f = t + i * 256;
        int r = f >> 5, k4 = f & 31;
        int gr = row0 + r;
        float4 v = make_float4(0.f, 0.f, 0.f, 0.f);
        if (gr < nrows) v = ((const float4*)X)[(size_t)gr * 32 + k4];
        if (relu_in) {
            v.x = fmaxf(v.x, 0.f); v.y = fmaxf(v.y, 0.f);
            v.z = fmaxf(v.z, 0.f); v.w = fmaxf(v.w, 0.f);
        }
        ((float4*)xs)[f] = v;
    }
    __syncthreads();   // the only barrier

    const float4* Wv = (const float4*)W;   // W[k][c] row-major, 32 float4/row
#pragma unroll 2
    for (int k4 = 0; k4 < 32; ++k4) {
        float4 b0 = Wv[(k4 * 4 + 0) * 32 + tc];
        float4 b1 = Wv[(k4 * 4 + 1) * 32 + tc];
        float4 b2 = Wv[(k4 * 4 + 2) * 32 + tc];
        float4 b3 = Wv[(k4 * 4 + 3) * 32 + tc];
#pragma unroll
        for (int i = 0; i < 8; ++i) {
            float4 a = *(const float4*)&xs[(tr * 8 + i) * 128 + k4 * 4];
            acc[i][0] += a.x * b0.x + a.y * b1.x + a.z * b2.x + a.w * b3.x;
            acc[i][1] += a.x * b0.y + a.y * b1.y + a.z * b2.y + a.w * b3.y;
            acc[i][2] += a.x * b0.z + a.y * b1.z + a.z * b2.z + a.w * b3.z;
            acc[i][3] += a.x * b0.w + a.y * b1.w + a.z * b2.w + a.w * b3.w;
        }
    }

#pragma unroll
    for (int i = 0; i < 8; ++i) {
        int gr = row0 + tr * 8 + i;
        if (gr < nrows)
            ((float4*)HW)[(size_t)gr * 32 + tc] =
                make_float4(acc[i][0], acc[i][1], acc[i][2], acc[i][3]);
    }
}

// pull-aggregation: 32 threads per node, float4 per thread, register acc.
// acc init = hw[g]*dis[g]^2 + bias (self-loop folded in). Single write/elem.
__global__ __launch_bounds__(256) void k_gather(const float* __restrict__ HW,
                                                const int* __restrict__ row_ptr,
                                                const int* __restrict__ src_csr,
                                                const float* __restrict__ norm_csr,
                                                const float* __restrict__ dis,
                                                const float* __restrict__ bias,
                                                float* __restrict__ AGG, int nN) {
    int g = blockIdx.x * 8 + (threadIdx.x >> 5);
    if (g >= nN) return;
    int f4 = threadIdx.x & 31;
    int beg = row_ptr[g], end = row_ptr[g + 1];
    float dn = dis[g];
    float sn = dn * dn;
    float4 bv = ((const float4*)bias)[f4];
    float4 sv = ((const float4*)HW)[(size_t)g * 32 + f4];
    float4 acc = make_float4(sv.x * sn + bv.x, sv.y * sn + bv.y,
                             sv.z * sn + bv.z, sv.w * sn + bv.w);
    int e = beg;
    for (; e + 3 < end; e += 4) {  // 4-way unroll for memory-level parallelism
        int s0 = src_csr[e], s1 = src_csr[e + 1];
        int s2 = src_csr[e + 2], s3 = src_csr[e + 3];
        float n0 = norm_csr[e], n1 = norm_csr[e + 1];
        float n2 = norm_csr[e + 2], n3 = norm_csr[e + 3];
        float4 v0 = ((const float4*)HW)[(size_t)s0 * 32 + f4];
        float4 v1 = ((const float4*)HW)[(size_t)s1 * 32 + f4];
        float4 v2 = ((const float4*)HW)[(size_t)s2 * 32 + f4];
        float4 v3 = ((const float4*)HW)[(size_t)s3 * 32 + f4];
        acc.x += v0.x * n0 + v1.x * n1 + v2.x * n2 + v3.x * n3;
        acc.y += v0.y * n0 + v1.y * n1 + v2.y * n2 + v3.y * n3;
        acc.z += v0.z * n0 + v1.z * n1 + v2.z * n2 + v3.z * n3;
        acc.w += v0.w * n0 + v1.w * n1 + v2.w * n2 + v3.w * n3;
    }
    for (; e < end; ++e) {
        int s = src_csr[e];
        float nv = norm_csr[e];
        float4 v = ((const float4*)HW)[(size_t)s * 32 + f4];
        acc.x += v.x * nv; acc.y += v.y * nv;
        acc.z += v.z * nv; acc.w += v.w * nv;
    }
    ((float4*)AGG)[(size_t)g * 32 + f4] = acc;
}

// layer 3: hw3[n] = dot(relu(h2[n,:]), W3)
__global__ __launch_bounds__(256) void k_gemv(const float* __restrict__ H,
                                              const float* __restrict__ W3,
                                              float* __restrict__ hw3, int nN) {
    int wid = (blockIdx.x * 256 + threadIdx.x) >> 6;
    int lane = threadIdx.x & 63;
    if (wid >= nN) return;
    float v0 = fmaxf(H[(size_t)wid * 128 + lane], 0.f);
    float v1 = fmaxf(H[(size_t)wid * 128 + 64 + lane], 0.f);
    float sum = v0 * W3[lane] + v1 * W3[64 + lane];
#pragma unroll
    for (int off = 32; off > 0; off >>= 1) sum += __shfl_down(sum, off);
    if (lane == 0) hw3[wid] = sum;
}

// scalar pull-aggregation + self-loop + bias + final relu -> d_out
__global__ __launch_bounds__(256) void k_gather3(const float* __restrict__ hw3,
                                                 const int* __restrict__ row_ptr,
                                                 const int* __restrict__ src_csr,
                                                 const float* __restrict__ norm_csr,
                                                 const float* __restrict__ dis,
                                                 const float* __restrict__ b3,
                                                 float* __restrict__ out, int nN) {
    int i = blockIdx.x * 256 + threadIdx.x;
    if (i >= nN) return;
    float dn = dis[i];
    float acc = hw3[i] * dn * dn + b3[0];
    int beg = row_ptr[i], end = row_ptr[i + 1];
    for (int e = beg; e < end; ++e) acc += hw3[src_csr[e]] * norm_csr[e];
    out[i] = fmaxf(acc, 0.f);
}

extern "C" void kernel_launch(void* const* d_in, const int* in_sizes, int n_in,
                              void* d_out, int out_size, void* d_ws, size_t ws_size,
                              hipStream_t stream) {
    const float* x  = (const float*)d_in[0];
    const int*   ei = (const int*)d_in[1];
    const float* W1 = (const float*)d_in[2];
    const float* b1 = (const float*)d_in[3];
    const float* W2 = (const float*)d_in[4];
    const float* b2 = (const float*)d_in[5];
    const float* W3 = (const float*)d_in[6];
    const float* b3 = (const float*)d_in[7];

    const int nN = in_sizes[0] / 128;
    const int nE = in_sizes[1] / 2;
    const int* src = ei;
    const int* dst = ei + nE;

    const int nB = (nN + 255) / 256;   // scan blocks

    // workspace layout
    char* p = (char*)d_ws;
    int*   cnt      = (int*)p;            p += (size_t)nN * 4;
    int*   cursor   = (int*)p;            p += (size_t)nN * 4;
    int*   excl     = (int*)p;            p += (size_t)nN * 4;
    int*   blk_sum  = (int*)p;            p += (size_t)(nB + 1) * 4;
    int*   row_ptr  = (int*)p;            p += (size_t)(nN + 1) * 4;
    int*   src_csr  = (int*)p;            p += (size_t)nE * 4;
    float* norm_csr = (float*)p;          p += (size_t)nE * 4;
    float* dis      = (float*)p;          p += (size_t)nN * 4;
    float* bufA     = (float*)p;          p += (size_t)nN * 128 * 4;  // hw
    float* bufB     = (float*)p;          p += (size_t)nN * 128 * 4;  // h / agg
    float* hw3      = bufA;               // bufA free by the time gemv runs

    const int BE  = (nE + 255) / 256;
    const int BN  = (nN + 255) / 256;
    const int BG  = (nN + 63) / 64;
    const int BGA = (nN + 7) / 8;
    const int BGV = (nN + 3) / 4;

    // --- CSR build + norm precompute ---
    hipMemsetAsync(cnt, 0, (size_t)nN * sizeof(int), stream);
    k_count   <<<BE, 256, 0, stream>>>(dst, cnt, nE);
    k_rsqrt   <<<BN, 256, 0, stream>>>(cnt, dis, nN);
    k_scan_blk<<<nB, 256, 0, stream>>>(cnt, excl, blk_sum, nN);
    k_scan_top<<<1, 256, 0, stream>>>(blk_sum, nB);
    k_scan_add<<<nB, 256, 0, stream>>>(excl, blk_sum, row_ptr, cursor, nN, nB);
    k_bin     <<<BE, 256, 0, stream>>>(src, dst, dis, cursor, src_csr, norm_csr, nE);

    // --- layer 1: x -> bufB ---
    k_gemm128<<<BG, 256, 0, stream>>>(x, W1, bufA, nN, 0);
    k_gather <<<BGA, 256, 0, stream>>>(bufA, row_ptr, src_csr, norm_csr, dis, b1, bufB, nN);

    // --- layer 2: relu(bufB) -> bufB ---
    k_gemm128<<<BG, 256, 0, stream>>>(bufB, W2, bufA, nN, 1);
    k_gather <<<BGA, 256, 0, stream>>>(bufA, row_ptr, src_csr, norm_csr, dis, b2, bufB, nN);

    // --- layer 3: relu(bufB) -> d_out ---
    k_gemv   <<<BGV, 256, 0, stream>>>(bufB, W3, hw3, nN);
    k_gather3<<<BN, 256, 0, stream>>>(hw3, row_ptr, src_csr, norm_csr, dis, b3,
                                      (float*)d_out, nN);
}

// Round 7
// 342.500 us; speedup vs baseline: 2.1324x; 1.0028x over previous
//
#include <hip/hip_runtime.h>

// ---------------------------------------------------------------------------
// 3-layer GCN, CSR-gather formulation with dis-prescaling:
//   HWS[r] = dis[r] * (relu?(X_r) @ W)          (GEMM epilogue scales)
//   agg[d] = dis[d] * (sum_{e in CSR[d]} HWS[src_e] + HWS[d]) + b
// -> gather needs NO per-edge norm value, only src indices.
// Lessons: R4/R5: __launch_bounds__ min-waves caps VGPR at 256/w -> spills;
// R6: occupancy via small LDS footprint (32KB, W from L2) is the right lever.
// ---------------------------------------------------------------------------

__global__ __launch_bounds__(256) void k_count(const int* __restrict__ dst,
                                               int* __restrict__ cnt, int nE) {
    int e = blockIdx.x * 256 + threadIdx.x;
    if (e < nE) atomicAdd(&cnt[dst[e]], 1);
}

__global__ __launch_bounds__(256) void k_rsqrt(const int* __restrict__ cnt,
                                               float* __restrict__ dis, int nN) {
    int i = blockIdx.x * 256 + threadIdx.x;
    if (i < nN) dis[i] = rsqrtf((float)cnt[i] + 1.0f);
}

// hierarchical scan, stage 1: per-block (256-wide) exclusive scan + block sum
__global__ __launch_bounds__(256) void k_scan_blk(const int* __restrict__ cnt,
                                                  int* __restrict__ excl,
                                                  int* __restrict__ blk_sum, int nN) {
    __shared__ int sm[256];
    const int t = threadIdx.x;
    int i = blockIdx.x * 256 + t;
    int v = (i < nN) ? cnt[i] : 0;
    sm[t] = v;
    __syncthreads();
#pragma unroll
    for (int off = 1; off < 256; off <<= 1) {
        int x = (t >= off) ? sm[t - off] : 0;
        __syncthreads();
        sm[t] += x;
        __syncthreads();
    }
    if (i < nN) excl[i] = sm[t] - v;
    if (t == 255) blk_sum[blockIdx.x] = sm[255];
}

// stage 2: single small block scans the block sums (nB <= 256)
__global__ __launch_bounds__(256) void k_scan_top(int* __restrict__ blk_sum, int nB) {
    __shared__ int sm[256];
    const int t = threadIdx.x;
    int v = (t < nB) ? blk_sum[t] : 0;
    sm[t] = v;
    __syncthreads();
#pragma unroll
    for (int off = 1; off < 256; off <<= 1) {
        int x = (t >= off) ? sm[t - off] : 0;
        __syncthreads();
        sm[t] += x;
        __syncthreads();
    }
    if (t < nB) blk_sum[t] = sm[t] - v;   // exclusive offsets in place
    if (t == 0) blk_sum[nB] = sm[255];    // grand total
}

// stage 3: add block offsets -> row_ptr + cursor copy
__global__ __launch_bounds__(256) void k_scan_add(const int* __restrict__ excl,
                                                  const int* __restrict__ blk_sum,
                                                  int* __restrict__ row_ptr,
                                                  int* __restrict__ cursor,
                                                  int nN, int nB) {
    int i = blockIdx.x * 256 + threadIdx.x;
    if (i < nN) {
        int v = excl[i] + blk_sum[i >> 8];
        row_ptr[i] = v;
        cursor[i] = v;
    }
    if (i == 0) row_ptr[nN] = blk_sum[nB];
}

// bin edges by dst: only src index is stored (no norm needed anymore)
__global__ __launch_bounds__(256) void k_bin(const int* __restrict__ src,
                                             const int* __restrict__ dst,
                                             int* __restrict__ cursor,
                                             int* __restrict__ src_csr, int nE) {
    int e = blockIdx.x * 256 + threadIdx.x;
    if (e >= nE) return;
    int s = src[e], d = dst[e];
    int pos = atomicAdd(&cursor[d], 1);
    src_csr[pos] = s;
}

// HWS = dis[row] * ((relu?(X)) @ W)   [nrows x 128] @ [128 x 128]
// X tile (64 rows) in LDS; W straight from global (L2-hot, broadcast).
// One barrier; 32KB LDS -> 5 blocks/CU. No forced launch bounds (R4/R5).
__global__ __launch_bounds__(256) void k_gemm128(const float* __restrict__ X,
                                                 const float* __restrict__ W,
                                                 const float* __restrict__ dis,
                                                 float* __restrict__ HWS,
                                                 int nrows, int relu_in) {
    __shared__ float xs[64 * 128];   // 32 KB
    const int t = threadIdx.x;
    const int row0 = blockIdx.x * 64;
    const int tr = t >> 5;   // 0..7  -> 8 rows each
    const int tc = t & 31;   // 0..31 -> 4 cols each

    float acc[8][4];
#pragma unroll
    for (int i = 0; i < 8; ++i)
#pragma unroll
        for (int c = 0; c < 4; ++c) acc[i][c] = 0.f;

#pragma unroll
    for (int i = 0; i < 8; ++i) {
        int f = t + i * 256;
        int r = f >> 5, k4 = f & 31;
        int gr = row0 + r;
        float4 v = make_float4(0.f, 0.f, 0.f, 0.f);
        if (gr < nrows) v = ((const float4*)X)[(size_t)gr * 32 + k4];
        if (relu_in) {
            v.x = fmaxf(v.x, 0.f); v.y = fmaxf(v.y, 0.f);
            v.z = fmaxf(v.z, 0.f); v.w = fmaxf(v.w, 0.f);
        }
        ((float4*)xs)[f] = v;
    }
    __syncthreads();   // the only barrier

    const float4* Wv = (const float4*)W;   // W[k][c] row-major, 32 float4/row
#pragma unroll 2
    for (int k4 = 0; k4 < 32; ++k4) {
        float4 b0 = Wv[(k4 * 4 + 0) * 32 + tc];
        float4 b1 = Wv[(k4 * 4 + 1) * 32 + tc];
        float4 b2 = Wv[(k4 * 4 + 2) * 32 + tc];
        float4 b3 = Wv[(k4 * 4 + 3) * 32 + tc];
#pragma unroll
        for (int i = 0; i < 8; ++i) {
            float4 a = *(const float4*)&xs[(tr * 8 + i) * 128 + k4 * 4];
            acc[i][0] += a.x * b0.x + a.y * b1.x + a.z * b2.x + a.w * b3.x;
            acc[i][1] += a.x * b0.y + a.y * b1.y + a.z * b2.y + a.w * b3.y;
            acc[i][2] += a.x * b0.z + a.y * b1.z + a.z * b2.z + a.w * b3.z;
            acc[i][3] += a.x * b0.w + a.y * b1.w + a.z * b2.w + a.w * b3.w;
        }
    }

#pragma unroll
    for (int i = 0; i < 8; ++i) {
        int gr = row0 + tr * 8 + i;
        if (gr < nrows) {
            float dn = dis[gr];
            ((float4*)HWS)[(size_t)gr * 32 + tc] =
                make_float4(acc[i][0] * dn, acc[i][1] * dn,
                            acc[i][2] * dn, acc[i][3] * dn);
        }
    }
}

// pull-aggregation: half-wave per node, float4 per lane, register acc.
// acc = HWS[g] + sum HWS[src]; out = dis[g]*acc + bias.
// 8/4/1 batched edge loads for memory-level parallelism (L3-latency hiding).
__global__ __launch_bounds__(256) void k_gather(const float* __restrict__ HWS,
                                                const int* __restrict__ row_ptr,
                                                const int* __restrict__ src_csr,
                                                const float* __restrict__ dis,
                                                const float* __restrict__ bias,
                                                float* __restrict__ AGG, int nN) {
    int g = blockIdx.x * 8 + (threadIdx.x >> 5);
    if (g >= nN) return;
    int f4 = threadIdx.x & 31;
    int beg = row_ptr[g], end = row_ptr[g + 1];
    const float4* Hv = (const float4*)HWS;
    float4 acc = Hv[(size_t)g * 32 + f4];   // self-loop term (pre-scaled)
    int e = beg;
    for (; e + 8 <= end; e += 8) {
        int s[8];
#pragma unroll
        for (int j = 0; j < 8; ++j) s[j] = src_csr[e + j];
        float4 v[8];
#pragma unroll
        for (int j = 0; j < 8; ++j) v[j] = Hv[(size_t)s[j] * 32 + f4];
#pragma unroll
        for (int j = 0; j < 8; ++j) {
            acc.x += v[j].x; acc.y += v[j].y;
            acc.z += v[j].z; acc.w += v[j].w;
        }
    }
    if (e + 4 <= end) {
        int s[4];
#pragma unroll
        for (int j = 0; j < 4; ++j) s[j] = src_csr[e + j];
        float4 v[4];
#pragma unroll
        for (int j = 0; j < 4; ++j) v[j] = Hv[(size_t)s[j] * 32 + f4];
#pragma unroll
        for (int j = 0; j < 4; ++j) {
            acc.x += v[j].x; acc.y += v[j].y;
            acc.z += v[j].z; acc.w += v[j].w;
        }
        e += 4;
    }
    for (; e < end; ++e) {
        float4 v = Hv[(size_t)src_csr[e] * 32 + f4];
        acc.x += v.x; acc.y += v.y; acc.z += v.z; acc.w += v.w;
    }
    float dn = dis[g];
    float4 bv = ((const float4*)bias)[f4];
    ((float4*)AGG)[(size_t)g * 32 + f4] =
        make_float4(acc.x * dn + bv.x, acc.y * dn + bv.y,
                    acc.z * dn + bv.z, acc.w * dn + bv.w);
}

// layer 3: hw3s[n] = dis[n] * dot(relu(h2[n,:]), W3)
__global__ __launch_bounds__(256) void k_gemv(const float* __restrict__ H,
                                              const float* __restrict__ W3,
                                              const float* __restrict__ dis,
                                              float* __restrict__ hw3s, int nN) {
    int wid = (blockIdx.x * 256 + threadIdx.x) >> 6;
    int lane = threadIdx.x & 63;
    if (wid >= nN) return;
    float v0 = fmaxf(H[(size_t)wid * 128 + lane], 0.f);
    float v1 = fmaxf(H[(size_t)wid * 128 + 64 + lane], 0.f);
    float sum = v0 * W3[lane] + v1 * W3[64 + lane];
#pragma unroll
    for (int off = 32; off > 0; off >>= 1) sum += __shfl_down(sum, off);
    if (lane == 0) hw3s[wid] = sum * dis[wid];
}

// scalar pull-aggregation + final relu -> d_out
__global__ __launch_bounds__(256) void k_gather3(const float* __restrict__ hw3s,
                                                 const int* __restrict__ row_ptr,
                                                 const int* __restrict__ src_csr,
                                                 const float* __restrict__ dis,
                                                 const float* __restrict__ b3,
                                                 float* __restrict__ out, int nN) {
    int i = blockIdx.x * 256 + threadIdx.x;
    if (i >= nN) return;
    float acc = hw3s[i];
    int beg = row_ptr[i], end = row_ptr[i + 1];
    for (int e = beg; e < end; ++e) acc += hw3s[src_csr[e]];
    out[i] = fmaxf(acc * dis[i] + b3[0], 0.f);
}

extern "C" void kernel_launch(void* const* d_in, const int* in_sizes, int n_in,
                              void* d_out, int out_size, void* d_ws, size_t ws_size,
                              hipStream_t stream) {
    const float* x  = (const float*)d_in[0];
    const int*   ei = (const int*)d_in[1];
    const float* W1 = (const float*)d_in[2];
    const float* b1 = (const float*)d_in[3];
    const float* W2 = (const float*)d_in[4];
    const float* b2 = (const float*)d_in[5];
    const float* W3 = (const float*)d_in[6];
    const float* b3 = (const float*)d_in[7];

    const int nN = in_sizes[0] / 128;
    const int nE = in_sizes[1] / 2;
    const int* src = ei;
    const int* dst = ei + nE;

    const int nB = (nN + 255) / 256;   // scan blocks

    // workspace layout
    char* p = (char*)d_ws;
    int*   cnt      = (int*)p;            p += (size_t)nN * 4;
    int*   cursor   = (int*)p;            p += (size_t)nN * 4;
    int*   excl     = (int*)p;            p += (size_t)nN * 4;
    int*   blk_sum  = (int*)p;            p += (size_t)(nB + 1) * 4;
    int*   row_ptr  = (int*)p;            p += (size_t)(nN + 1) * 4;
    int*   src_csr  = (int*)p;            p += (size_t)nE * 4;
    float* dis      = (float*)p;          p += (size_t)nN * 4;
    float* bufA     = (float*)p;          p += (size_t)nN * 128 * 4;  // HWS
    float* bufB     = (float*)p;          p += (size_t)nN * 128 * 4;  // h / agg
    float* hw3s     = bufA;               // bufA free by the time gemv runs

    const int BE  = (nE + 255) / 256;
    const int BN  = (nN + 255) / 256;
    const int BG  = (nN + 63) / 64;
    const int BGA = (nN + 7) / 8;
    const int BGV = (nN + 3) / 4;

    // --- CSR build + norm precompute ---
    hipMemsetAsync(cnt, 0, (size_t)nN * sizeof(int), stream);
    k_count   <<<BE, 256, 0, stream>>>(dst, cnt, nE);
    k_rsqrt   <<<BN, 256, 0, stream>>>(cnt, dis, nN);
    k_scan_blk<<<nB, 256, 0, stream>>>(cnt, excl, blk_sum, nN);
    k_scan_top<<<1, 256, 0, stream>>>(blk_sum, nB);
    k_scan_add<<<nB, 256, 0, stream>>>(excl, blk_sum, row_ptr, cursor, nN, nB);
    k_bin     <<<BE, 256, 0, stream>>>(src, dst, cursor, src_csr, nE);

    // --- layer 1: x -> bufB ---
    k_gemm128<<<BG, 256, 0, stream>>>(x, W1, dis, bufA, nN, 0);
    k_gather <<<BGA, 256, 0, stream>>>(bufA, row_ptr, src_csr, dis, b1, bufB, nN);

    // --- layer 2: relu(bufB) -> bufB ---
    k_gemm128<<<BG, 256, 0, stream>>>(bufB, W2, dis, bufA, nN, 1);
    k_gather <<<BGA, 256, 0, stream>>>(bufA, row_ptr, src_csr, dis, b2, bufB, nN);

    // --- layer 3: relu(bufB) -> d_out ---
    k_gemv   <<<BGV, 256, 0, stream>>>(bufB, W3, dis, hw3s, nN);
    k_gather3<<<BN, 256, 0, stream>>>(hw3s, row_ptr, src_csr, dis, b3,
                                      (float*)d_out, nN);
}

// Round 8
// 301.610 us; speedup vs baseline: 2.4215x; 1.1356x over previous
//
#include <hip/hip_runtime.h>
#include <hip/hip_fp16.h>

// ---------------------------------------------------------------------------
// 3-layer GCN, CSR-gather formulation with dis-prescaling + fp16 HWS:
//   HWS[r] = half( dis[r] * (relu?(X_r) @ W) )   (GEMM epilogue scales+casts)
//   agg[d] = dis[d] * (sum_{e in CSR[d]} HWS[src_e] + HWS[d]) + b   (fp32 acc)
// HWS is only ever consumed by the gather -> fp16 halves the random-gather
// bytes (the R7-measured bottleneck: 172MB L2-miss traffic @ ~3.1TB/s).
// Lessons: R4/R5: __launch_bounds__ min-waves caps VGPR at 256/w -> spills.
// ---------------------------------------------------------------------------

__global__ __launch_bounds__(256) void k_count(const int* __restrict__ dst,
                                               int* __restrict__ cnt, int nE) {
    int e = blockIdx.x * 256 + threadIdx.x;
    if (e < nE) atomicAdd(&cnt[dst[e]], 1);
}

__global__ __launch_bounds__(256) void k_rsqrt(const int* __restrict__ cnt,
                                               float* __restrict__ dis, int nN) {
    int i = blockIdx.x * 256 + threadIdx.x;
    if (i < nN) dis[i] = rsqrtf((float)cnt[i] + 1.0f);
}

// hierarchical scan, stage 1: per-block (256-wide) exclusive scan + block sum
__global__ __launch_bounds__(256) void k_scan_blk(const int* __restrict__ cnt,
                                                  int* __restrict__ excl,
                                                  int* __restrict__ blk_sum, int nN) {
    __shared__ int sm[256];
    const int t = threadIdx.x;
    int i = blockIdx.x * 256 + t;
    int v = (i < nN) ? cnt[i] : 0;
    sm[t] = v;
    __syncthreads();
#pragma unroll
    for (int off = 1; off < 256; off <<= 1) {
        int x = (t >= off) ? sm[t - off] : 0;
        __syncthreads();
        sm[t] += x;
        __syncthreads();
    }
    if (i < nN) excl[i] = sm[t] - v;
    if (t == 255) blk_sum[blockIdx.x] = sm[255];
}

// stage 2: single small block scans the block sums (nB <= 256)
__global__ __launch_bounds__(256) void k_scan_top(int* __restrict__ blk_sum, int nB) {
    __shared__ int sm[256];
    const int t = threadIdx.x;
    int v = (t < nB) ? blk_sum[t] : 0;
    sm[t] = v;
    __syncthreads();
#pragma unroll
    for (int off = 1; off < 256; off <<= 1) {
        int x = (t >= off) ? sm[t - off] : 0;
        __syncthreads();
        sm[t] += x;
        __syncthreads();
    }
    if (t < nB) blk_sum[t] = sm[t] - v;   // exclusive offsets in place
    if (t == 0) blk_sum[nB] = sm[255];    // grand total
}

// stage 3: add block offsets -> row_ptr + cursor copy
__global__ __launch_bounds__(256) void k_scan_add(const int* __restrict__ excl,
                                                  const int* __restrict__ blk_sum,
                                                  int* __restrict__ row_ptr,
                                                  int* __restrict__ cursor,
                                                  int nN, int nB) {
    int i = blockIdx.x * 256 + threadIdx.x;
    if (i < nN) {
        int v = excl[i] + blk_sum[i >> 8];
        row_ptr[i] = v;
        cursor[i] = v;
    }
    if (i == 0) row_ptr[nN] = blk_sum[nB];
}

// bin edges by dst: only src index is stored
__global__ __launch_bounds__(256) void k_bin(const int* __restrict__ src,
                                             const int* __restrict__ dst,
                                             int* __restrict__ cursor,
                                             int* __restrict__ src_csr, int nE) {
    int e = blockIdx.x * 256 + threadIdx.x;
    if (e >= nE) return;
    int s = src[e], d = dst[e];
    int pos = atomicAdd(&cursor[d], 1);
    src_csr[pos] = s;
}

// HWS = half( dis[row] * ((relu?(X)) @ W) )   [nrows x 128] @ [128 x 128]
// X tile (64 rows) in LDS; W straight from global (L2-hot, broadcast).
// One barrier; 32KB LDS -> 5 blocks/CU. No forced launch bounds (R4/R5).
__global__ __launch_bounds__(256) void k_gemm128(const float* __restrict__ X,
                                                 const float* __restrict__ W,
                                                 const float* __restrict__ dis,
                                                 __half* __restrict__ HWS,
                                                 int nrows, int relu_in) {
    __shared__ float xs[64 * 128];   // 32 KB
    const int t = threadIdx.x;
    const int row0 = blockIdx.x * 64;
    const int tr = t >> 5;   // 0..7  -> 8 rows each
    const int tc = t & 31;   // 0..31 -> 4 cols each

    float acc[8][4];
#pragma unroll
    for (int i = 0; i < 8; ++i)
#pragma unroll
        for (int c = 0; c < 4; ++c) acc[i][c] = 0.f;

#pragma unroll
    for (int i = 0; i < 8; ++i) {
        int f = t + i * 256;
        int r = f >> 5, k4 = f & 31;
        int gr = row0 + r;
        float4 v = make_float4(0.f, 0.f, 0.f, 0.f);
        if (gr < nrows) v = ((const float4*)X)[(size_t)gr * 32 + k4];
        if (relu_in) {
            v.x = fmaxf(v.x, 0.f); v.y = fmaxf(v.y, 0.f);
            v.z = fmaxf(v.z, 0.f); v.w = fmaxf(v.w, 0.f);
        }
        ((float4*)xs)[f] = v;
    }
    __syncthreads();   // the only barrier

    const float4* Wv = (const float4*)W;   // W[k][c] row-major, 32 float4/row
#pragma unroll 2
    for (int k4 = 0; k4 < 32; ++k4) {
        float4 b0 = Wv[(k4 * 4 + 0) * 32 + tc];
        float4 b1 = Wv[(k4 * 4 + 1) * 32 + tc];
        float4 b2 = Wv[(k4 * 4 + 2) * 32 + tc];
        float4 b3 = Wv[(k4 * 4 + 3) * 32 + tc];
#pragma unroll
        for (int i = 0; i < 8; ++i) {
            float4 a = *(const float4*)&xs[(tr * 8 + i) * 128 + k4 * 4];
            acc[i][0] += a.x * b0.x + a.y * b1.x + a.z * b2.x + a.w * b3.x;
            acc[i][1] += a.x * b0.y + a.y * b1.y + a.z * b2.y + a.w * b3.y;
            acc[i][2] += a.x * b0.z + a.y * b1.z + a.z * b2.z + a.w * b3.z;
            acc[i][3] += a.x * b0.w + a.y * b1.w + a.z * b2.w + a.w * b3.w;
        }
    }

#pragma unroll
    for (int i = 0; i < 8; ++i) {
        int gr = row0 + tr * 8 + i;
        if (gr < nrows) {
            float dn = dis[gr];
            __half2 h01 = __float22half2_rn(make_float2(acc[i][0] * dn, acc[i][1] * dn));
            __half2 h23 = __float22half2_rn(make_float2(acc[i][2] * dn, acc[i][3] * dn));
            float2 packed;
            *(__half2*)&packed.x = h01;
            *(__half2*)&packed.y = h23;
            ((float2*)HWS)[(size_t)gr * 32 + tc] = packed;  // 8B/lane, coalesced
        }
    }
}

// pull-aggregation: half-wave per node, 4 halves (8B) per lane, fp32 acc.
// acc = HWS[g] + sum HWS[src]; out = dis[g]*acc + bias.
__global__ __launch_bounds__(256) void k_gather(const __half* __restrict__ HWS,
                                                const int* __restrict__ row_ptr,
                                                const int* __restrict__ src_csr,
                                                const float* __restrict__ dis,
                                                const float* __restrict__ bias,
                                                float* __restrict__ AGG, int nN) {
    int g = blockIdx.x * 8 + (threadIdx.x >> 5);
    if (g >= nN) return;
    int f4 = threadIdx.x & 31;
    int beg = row_ptr[g], end = row_ptr[g + 1];
    const float2* Hv = (const float2*)HWS;   // 4 halves per float2, 32 per row

    float4 acc;
    {
        float2 r = Hv[(size_t)g * 32 + f4];   // self-loop term (pre-scaled)
        float2 lo = __half22float2(*(__half2*)&r.x);
        float2 hi = __half22float2(*(__half2*)&r.y);
        acc = make_float4(lo.x, lo.y, hi.x, hi.y);
    }

    int e = beg;
    for (; e + 8 <= end; e += 8) {
        int s[8];
#pragma unroll
        for (int j = 0; j < 8; ++j) s[j] = src_csr[e + j];
        float2 r[8];
#pragma unroll
        for (int j = 0; j < 8; ++j) r[j] = Hv[(size_t)s[j] * 32 + f4];
#pragma unroll
        for (int j = 0; j < 8; ++j) {
            float2 lo = __half22float2(*(__half2*)&r[j].x);
            float2 hi = __half22float2(*(__half2*)&r[j].y);
            acc.x += lo.x; acc.y += lo.y; acc.z += hi.x; acc.w += hi.y;
        }
    }
    if (e + 4 <= end) {
        int s[4];
#pragma unroll
        for (int j = 0; j < 4; ++j) s[j] = src_csr[e + j];
        float2 r[4];
#pragma unroll
        for (int j = 0; j < 4; ++j) r[j] = Hv[(size_t)s[j] * 32 + f4];
#pragma unroll
        for (int j = 0; j < 4; ++j) {
            float2 lo = __half22float2(*(__half2*)&r[j].x);
            float2 hi = __half22float2(*(__half2*)&r[j].y);
            acc.x += lo.x; acc.y += lo.y; acc.z += hi.x; acc.w += hi.y;
        }
        e += 4;
    }
    for (; e < end; ++e) {
        float2 r = Hv[(size_t)src_csr[e] * 32 + f4];
        float2 lo = __half22float2(*(__half2*)&r.x);
        float2 hi = __half22float2(*(__half2*)&r.y);
        acc.x += lo.x; acc.y += lo.y; acc.z += hi.x; acc.w += hi.y;
    }

    float dn = dis[g];
    float4 bv = ((const float4*)bias)[f4];
    ((float4*)AGG)[(size_t)g * 32 + f4] =
        make_float4(acc.x * dn + bv.x, acc.y * dn + bv.y,
                    acc.z * dn + bv.z, acc.w * dn + bv.w);
}

// layer 3: hw3s[n] = dis[n] * dot(relu(h2[n,:]), W3)   (fp32 throughout)
__global__ __launch_bounds__(256) void k_gemv(const float* __restrict__ H,
                                              const float* __restrict__ W3,
                                              const float* __restrict__ dis,
                                              float* __restrict__ hw3s, int nN) {
    int wid = (blockIdx.x * 256 + threadIdx.x) >> 6;
    int lane = threadIdx.x & 63;
    if (wid >= nN) return;
    float v0 = fmaxf(H[(size_t)wid * 128 + lane], 0.f);
    float v1 = fmaxf(H[(size_t)wid * 128 + 64 + lane], 0.f);
    float sum = v0 * W3[lane] + v1 * W3[64 + lane];
#pragma unroll
    for (int off = 32; off > 0; off >>= 1) sum += __shfl_down(sum, off);
    if (lane == 0) hw3s[wid] = sum * dis[wid];
}

// scalar pull-aggregation + final relu -> d_out
__global__ __launch_bounds__(256) void k_gather3(const float* __restrict__ hw3s,
                                                 const int* __restrict__ row_ptr,
                                                 const int* __restrict__ src_csr,
                                                 const float* __restrict__ dis,
                                                 const float* __restrict__ b3,
                                                 float* __restrict__ out, int nN) {
    int i = blockIdx.x * 256 + threadIdx.x;
    if (i >= nN) return;
    float acc = hw3s[i];
    int beg = row_ptr[i], end = row_ptr[i + 1];
    for (int e = beg; e < end; ++e) acc += hw3s[src_csr[e]];
    out[i] = fmaxf(acc * dis[i] + b3[0], 0.f);
}

extern "C" void kernel_launch(void* const* d_in, const int* in_sizes, int n_in,
                              void* d_out, int out_size, void* d_ws, size_t ws_size,
                              hipStream_t stream) {
    const float* x  = (const float*)d_in[0];
    const int*   ei = (const int*)d_in[1];
    const float* W1 = (const float*)d_in[2];
    const float* b1 = (const float*)d_in[3];
    const float* W2 = (const float*)d_in[4];
    const float* b2 = (const float*)d_in[5];
    const float* W3 = (const float*)d_in[6];
    const float* b3 = (const float*)d_in[7];

    const int nN = in_sizes[0] / 128;
    const int nE = in_sizes[1] / 2;
    const int* src = ei;
    const int* dst = ei + nE;

    const int nB = (nN + 255) / 256;   // scan blocks

    // workspace layout
    char* p = (char*)d_ws;
    int*    cnt      = (int*)p;           p += (size_t)nN * 4;
    int*    cursor   = (int*)p;           p += (size_t)nN * 4;
    int*    excl     = (int*)p;           p += (size_t)nN * 4;
    int*    blk_sum  = (int*)p;           p += (size_t)(nB + 1) * 4;
    int*    row_ptr  = (int*)p;           p += (size_t)(nN + 1) * 4;
    int*    src_csr  = (int*)p;           p += (size_t)nE * 4;
    float*  dis      = (float*)p;         p += (size_t)nN * 4;
    float*  hw3s     = (float*)p;         p += (size_t)nN * 4;
    __half* bufA     = (__half*)p;        p += (size_t)nN * 128 * 2;  // HWS fp16
    p = (char*)(((uintptr_t)p + 255) & ~(uintptr_t)255);
    float*  bufB     = (float*)p;         p += (size_t)nN * 128 * 4;  // h / agg

    const int BE  = (nE + 255) / 256;
    const int BN  = (nN + 255) / 256;
    const int BG  = (nN + 63) / 64;
    const int BGA = (nN + 7) / 8;
    const int BGV = (nN + 3) / 4;

    // --- CSR build + norm precompute ---
    hipMemsetAsync(cnt, 0, (size_t)nN * sizeof(int), stream);
    k_count   <<<BE, 256, 0, stream>>>(dst, cnt, nE);
    k_rsqrt   <<<BN, 256, 0, stream>>>(cnt, dis, nN);
    k_scan_blk<<<nB, 256, 0, stream>>>(cnt, excl, blk_sum, nN);
    k_scan_top<<<1, 256, 0, stream>>>(blk_sum, nB);
    k_scan_add<<<nB, 256, 0, stream>>>(excl, blk_sum, row_ptr, cursor, nN, nB);
    k_bin     <<<BE, 256, 0, stream>>>(src, dst, cursor, src_csr, nE);

    // --- layer 1: x -> bufB ---
    k_gemm128<<<BG, 256, 0, stream>>>(x, W1, dis, bufA, nN, 0);
    k_gather <<<BGA, 256, 0, stream>>>(bufA, row_ptr, src_csr, dis, b1, bufB, nN);

    // --- layer 2: relu(bufB) -> bufB ---
    k_gemm128<<<BG, 256, 0, stream>>>(bufB, W2, dis, bufA, nN, 1);
    k_gather <<<BGA, 256, 0, stream>>>(bufA, row_ptr, src_csr, dis, b2, bufB, nN);

    // --- layer 3: relu(bufB) -> d_out ---
    k_gemv   <<<BGV, 256, 0, stream>>>(bufB, W3, dis, hw3s, nN);
    k_gather3<<<BN, 256, 0, stream>>>(hw3s, row_ptr, src_csr, dis, b3,
                                      (float*)d_out, nN);
}

// Round 10
// 267.171 us; speedup vs baseline: 2.7336x; 1.1289x over previous
//
#include <hip/hip_runtime.h>
#include <hip/hip_fp16.h>

// ---------------------------------------------------------------------------
// 3-layer GCN, CSR-gather, fp16 dataflow + MFMA GEMM:
//   Wt = half(W^T)  (per call)
//   HWS[r] = half( dis[r] * (relu?(A_r) @ W) )    -- MFMA f32_16x16x32_f16
//   AGG[d] = half( dis[d]*(sum HWS[src] + HWS[d]) + b )   -- fp32 acc gather
// Lessons: R4/R5 never force __launch_bounds__ min-waves (VGPR cap 256/w ->
// spills). R7/R8: gather is bytes-below-L2 bound; fp16 halves it.
// ---------------------------------------------------------------------------

typedef _Float16 v8h __attribute__((ext_vector_type(8)));
typedef float v4f __attribute__((ext_vector_type(4)));

__global__ __launch_bounds__(256) void k_count(const int* __restrict__ dst,
                                               int* __restrict__ cnt, int nE) {
    int e = blockIdx.x * 256 + threadIdx.x;
    if (e < nE) atomicAdd(&cnt[dst[e]], 1);
}

// scan stage 1 + fused dis = rsqrt(cnt+1)
__global__ __launch_bounds__(256) void k_scan_blk(const int* __restrict__ cnt,
                                                  float* __restrict__ dis,
                                                  int* __restrict__ excl,
                                                  int* __restrict__ blk_sum, int nN) {
    __shared__ int sm[256];
    const int t = threadIdx.x;
    int i = blockIdx.x * 256 + t;
    int v = (i < nN) ? cnt[i] : 0;
    if (i < nN) dis[i] = rsqrtf((float)v + 1.0f);
    sm[t] = v;
    __syncthreads();
#pragma unroll
    for (int off = 1; off < 256; off <<= 1) {
        int x = (t >= off) ? sm[t - off] : 0;
        __syncthreads();
        sm[t] += x;
        __syncthreads();
    }
    if (i < nN) excl[i] = sm[t] - v;
    if (t == 255) blk_sum[blockIdx.x] = sm[255];
}

__global__ __launch_bounds__(256) void k_scan_top(int* __restrict__ blk_sum, int nB) {
    __shared__ int sm[256];
    const int t = threadIdx.x;
    int v = (t < nB) ? blk_sum[t] : 0;
    sm[t] = v;
    __syncthreads();
#pragma unroll
    for (int off = 1; off < 256; off <<= 1) {
        int x = (t >= off) ? sm[t - off] : 0;
        __syncthreads();
        sm[t] += x;
        __syncthreads();
    }
    if (t < nB) blk_sum[t] = sm[t] - v;
    if (t == 0) blk_sum[nB] = sm[255];
}

__global__ __launch_bounds__(256) void k_scan_add(const int* __restrict__ excl,
                                                  const int* __restrict__ blk_sum,
                                                  int* __restrict__ row_ptr,
                                                  int* __restrict__ cursor,
                                                  int nN, int nB) {
    int i = blockIdx.x * 256 + threadIdx.x;
    if (i < nN) {
        int v = excl[i] + blk_sum[i >> 8];
        row_ptr[i] = v;
        cursor[i] = v;
    }
    if (i == 0) row_ptr[nN] = blk_sum[nB];
}

__global__ __launch_bounds__(256) void k_bin(const int* __restrict__ src,
                                             const int* __restrict__ dst,
                                             int* __restrict__ cursor,
                                             int* __restrict__ src_csr, int nE) {
    int e = blockIdx.x * 256 + threadIdx.x;
    if (e >= nE) return;
    int s = src[e], d = dst[e];
    int pos = atomicAdd(&cursor[d], 1);
    src_csr[pos] = s;
}

// Wt[c*128+k] = half(W[k*128+c]) for W1 and W2 (128x128 each)
__global__ __launch_bounds__(256) void k_wcast(const float* __restrict__ W1,
                                               const float* __restrict__ W2,
                                               __half* __restrict__ Wt1,
                                               __half* __restrict__ Wt2) {
    int i = blockIdx.x * 256 + threadIdx.x;   // 16384
    int k = i >> 7, c = i & 127;
    Wt1[c * 128 + k] = __float2half(W1[i]);
    Wt2[c * 128 + k] = __float2half(W2[i]);
}

// MFMA GEMM: HWS = half( dis[row] * (relu?(A) @ W) ), A is [nrows x 128],
// Wt is half(W^T) [128c x 128k]. Block: 64 rows, 4 waves; wave w owns rows
// [row0+16w, +16), all 128 cols as 8 16-col tiles. LDS A-tile pitch 136
// halves (272B -> only 2-way bank aliasing on ds_read_b128, free).
// A source: fp32 (X16==null, no relu) or fp16 (with relu).
__global__ __launch_bounds__(256) void k_gemm_mfma(const float* __restrict__ X32,
                                                   const __half* __restrict__ X16,
                                                   const __half* __restrict__ Wt,
                                                   const float* __restrict__ dis,
                                                   __half* __restrict__ HWS,
                                                   int nrows) {
    __shared__ __half xs[64 * 136];
    const int t = threadIdx.x;
    const int row0 = blockIdx.x * 64;

    if (X16 == nullptr) {
        // fp32 source, no relu: 2048 float4 loads -> half4 stores
#pragma unroll
        for (int i = 0; i < 8; ++i) {
            int f = t + i * 256;
            int r = f >> 5, k4 = f & 31;
            int gr = row0 + r;
            float4 v = make_float4(0.f, 0.f, 0.f, 0.f);
            if (gr < nrows) v = ((const float4*)X32)[(size_t)gr * 32 + k4];
            __half2 h01 = __float22half2_rn(make_float2(v.x, v.y));
            __half2 h23 = __float22half2_rn(make_float2(v.z, v.w));
            float2 packed;
            *(__half2*)&packed.x = h01;
            *(__half2*)&packed.y = h23;
            *(float2*)&xs[r * 136 + k4 * 4] = packed;
        }
    } else {
        // fp16 source with relu: 1024 x 16B loads, relu on _Float16 lanes
#pragma unroll
        for (int i = 0; i < 4; ++i) {
            int f = t + i * 256;
            int r = f >> 4, k8 = f & 15;
            int gr = row0 + r;
            v8h raw = (v8h)(_Float16)0;
            if (gr < nrows) raw = ((const v8h*)X16)[(size_t)gr * 16 + k8];
#pragma unroll
            for (int j = 0; j < 8; ++j)
                raw[j] = raw[j] > (_Float16)0 ? raw[j] : (_Float16)0;
            *(v8h*)&xs[r * 136 + k8 * 8] = raw;
        }
    }
    __syncthreads();

    const int w = t >> 6;        // wave 0..3 -> rows [16w,16w+16)
    const int l = t & 63;
    const int mrow = l & 15;     // A row within tile / B col within tile / D col
    const int kq = l >> 4;       // quad: k-offset group, and D row group

    v8h a[4];
#pragma unroll
    for (int kk = 0; kk < 4; ++kk)
        a[kk] = *(const v8h*)&xs[(w * 16 + mrow) * 136 + kk * 32 + kq * 8];

    v4f acc[8];
#pragma unroll
    for (int c = 0; c < 8; ++c) acc[c] = (v4f){0.f, 0.f, 0.f, 0.f};

#pragma unroll
    for (int kk = 0; kk < 4; ++kk) {
#pragma unroll
        for (int c = 0; c < 8; ++c) {
            v8h b = *(const v8h*)&Wt[(size_t)(c * 16 + mrow) * 128 + kk * 32 + kq * 8];
            acc[c] = __builtin_amdgcn_mfma_f32_16x16x32_f16(a[kk], b, acc[c], 0, 0, 0);
        }
    }

    // epilogue: D[row=kq*4+r][col=mrow] per tile c
    float dn[4];
#pragma unroll
    for (int r = 0; r < 4; ++r) {
        int grow = row0 + w * 16 + kq * 4 + r;
        dn[r] = (grow < nrows) ? dis[grow] : 0.f;
    }
#pragma unroll
    for (int c = 0; c < 8; ++c) {
#pragma unroll
        for (int r = 0; r < 4; ++r) {
            int grow = row0 + w * 16 + kq * 4 + r;
            if (grow < nrows)
                HWS[(size_t)grow * 128 + c * 16 + mrow] =
                    __float2half(acc[c][r] * dn[r]);
        }
    }
}

// pull-aggregation: half-wave per node, 4 halves (8B) per lane, fp32 acc.
// AGG = half( dis[g]*(HWS[g] + sum HWS[src]) + bias )  (fp16 out, no relu --
// consumer applies relu)
__global__ __launch_bounds__(256) void k_gather(const __half* __restrict__ HWS,
                                                const int* __restrict__ row_ptr,
                                                const int* __restrict__ src_csr,
                                                const float* __restrict__ dis,
                                                const float* __restrict__ bias,
                                                __half* __restrict__ AGG, int nN) {
    int g = blockIdx.x * 8 + (threadIdx.x >> 5);
    if (g >= nN) return;
    int f4 = threadIdx.x & 31;
    int beg = row_ptr[g], end = row_ptr[g + 1];
    const float2* Hv = (const float2*)HWS;   // 4 halves per float2, 32 per row

    float4 acc;
    {
        float2 r = Hv[(size_t)g * 32 + f4];
        float2 lo = __half22float2(*(__half2*)&r.x);
        float2 hi = __half22float2(*(__half2*)&r.y);
        acc = make_float4(lo.x, lo.y, hi.x, hi.y);
    }

    int e = beg;
    for (; e + 8 <= end; e += 8) {
        int s[8];
#pragma unroll
        for (int j = 0; j < 8; ++j) s[j] = src_csr[e + j];
        float2 r[8];
#pragma unroll
        for (int j = 0; j < 8; ++j) r[j] = Hv[(size_t)s[j] * 32 + f4];
#pragma unroll
        for (int j = 0; j < 8; ++j) {
            float2 lo = __half22float2(*(__half2*)&r[j].x);
            float2 hi = __half22float2(*(__half2*)&r[j].y);
            acc.x += lo.x; acc.y += lo.y; acc.z += hi.x; acc.w += hi.y;
        }
    }
    if (e + 4 <= end) {
        int s[4];
#pragma unroll
        for (int j = 0; j < 4; ++j) s[j] = src_csr[e + j];
        float2 r[4];
#pragma unroll
        for (int j = 0; j < 4; ++j) r[j] = Hv[(size_t)s[j] * 32 + f4];
#pragma unroll
        for (int j = 0; j < 4; ++j) {
            float2 lo = __half22float2(*(__half2*)&r[j].x);
            float2 hi = __half22float2(*(__half2*)&r[j].y);
            acc.x += lo.x; acc.y += lo.y; acc.z += hi.x; acc.w += hi.y;
        }
        e += 4;
    }
    for (; e < end; ++e) {
        float2 r = Hv[(size_t)src_csr[e] * 32 + f4];
        float2 lo = __half22float2(*(__half2*)&r.x);
        float2 hi = __half22float2(*(__half2*)&r.y);
        acc.x += lo.x; acc.y += lo.y; acc.z += hi.x; acc.w += hi.y;
    }

    float dn = dis[g];
    float4 bv = ((const float4*)bias)[f4];
    __half2 o01 = __float22half2_rn(make_float2(acc.x * dn + bv.x, acc.y * dn + bv.y));
    __half2 o23 = __float22half2_rn(make_float2(acc.z * dn + bv.z, acc.w * dn + bv.w));
    float2 packed;
    *(__half2*)&packed.x = o01;
    *(__half2*)&packed.y = o23;
    ((float2*)AGG)[(size_t)g * 32 + f4] = packed;
}

// layer 3: hw3s[n] = dis[n] * dot(relu(h2[n,:]), W3);  h2 fp16
__global__ __launch_bounds__(256) void k_gemv(const __half* __restrict__ H,
                                              const float* __restrict__ W3,
                                              const float* __restrict__ dis,
                                              float* __restrict__ hw3s, int nN) {
    int wid = (blockIdx.x * 256 + threadIdx.x) >> 6;
    int lane = threadIdx.x & 63;
    if (wid >= nN) return;
    __half2 h = ((const __half2*)H)[(size_t)wid * 64 + lane];
    float2 f = __half22float2(h);
    f.x = fmaxf(f.x, 0.f);
    f.y = fmaxf(f.y, 0.f);
    float sum = f.x * W3[lane * 2] + f.y * W3[lane * 2 + 1];
#pragma unroll
    for (int off = 32; off > 0; off >>= 1) sum += __shfl_down(sum, off);
    if (lane == 0) hw3s[wid] = sum * dis[wid];
}

// scalar pull-aggregation + final relu -> d_out
__global__ __launch_bounds__(256) void k_gather3(const float* __restrict__ hw3s,
                                                 const int* __restrict__ row_ptr,
                                                 const int* __restrict__ src_csr,
                                                 const float* __restrict__ dis,
                                                 const float* __restrict__ b3,
                                                 float* __restrict__ out, int nN) {
    int i = blockIdx.x * 256 + threadIdx.x;
    if (i >= nN) return;
    float acc = hw3s[i];
    int beg = row_ptr[i], end = row_ptr[i + 1];
    for (int e = beg; e < end; ++e) acc += hw3s[src_csr[e]];
    out[i] = fmaxf(acc * dis[i] + b3[0], 0.f);
}

extern "C" void kernel_launch(void* const* d_in, const int* in_sizes, int n_in,
                              void* d_out, int out_size, void* d_ws, size_t ws_size,
                              hipStream_t stream) {
    const float* x  = (const float*)d_in[0];
    const int*   ei = (const int*)d_in[1];
    const float* W1 = (const float*)d_in[2];
    const float* b1 = (const float*)d_in[3];
    const float* W2 = (const float*)d_in[4];
    const float* b2 = (const float*)d_in[5];
    const float* W3 = (const float*)d_in[6];
    const float* b3 = (const float*)d_in[7];

    const int nN = in_sizes[0] / 128;
    const int nE = in_sizes[1] / 2;
    const int* src = ei;
    const int* dst = ei + nE;

    const int nB = (nN + 255) / 256;   // scan blocks

    // workspace layout
    char* p = (char*)d_ws;
    int*    cnt      = (int*)p;           p += (size_t)nN * 4;
    int*    cursor   = (int*)p;           p += (size_t)nN * 4;
    int*    excl     = (int*)p;           p += (size_t)nN * 4;
    int*    blk_sum  = (int*)p;           p += (size_t)(nB + 1) * 4;
    int*    row_ptr  = (int*)p;           p += (size_t)(nN + 1) * 4;
    int*    src_csr  = (int*)p;           p += (size_t)nE * 4;
    float*  dis      = (float*)p;         p += (size_t)nN * 4;
    float*  hw3s     = (float*)p;         p += (size_t)nN * 4;
    p = (char*)(((uintptr_t)p + 255) & ~(uintptr_t)255);
    __half* Wt1      = (__half*)p;        p += (size_t)128 * 128 * 2;
    __half* Wt2      = (__half*)p;        p += (size_t)128 * 128 * 2;
    __half* bufA     = (__half*)p;        p += (size_t)nN * 128 * 2;  // HWS
    p = (char*)(((uintptr_t)p + 255) & ~(uintptr_t)255);
    __half* bufB     = (__half*)p;        p += (size_t)nN * 128 * 2;  // AGG / h

    const int BE  = (nE + 255) / 256;
    const int BN  = (nN + 255) / 256;
    const int BG  = (nN + 63) / 64;
    const int BGA = (nN + 7) / 8;
    const int BGV = (nN + 3) / 4;

    // --- CSR build + norm precompute + weight cast ---
    hipMemsetAsync(cnt, 0, (size_t)nN * sizeof(int), stream);
    k_count   <<<BE, 256, 0, stream>>>(dst, cnt, nE);
    k_wcast   <<<64, 256, 0, stream>>>(W1, W2, Wt1, Wt2);
    k_scan_blk<<<nB, 256, 0, stream>>>(cnt, dis, excl, blk_sum, nN);
    k_scan_top<<<1, 256, 0, stream>>>(blk_sum, nB);
    k_scan_add<<<nB, 256, 0, stream>>>(excl, blk_sum, row_ptr, cursor, nN, nB);
    k_bin     <<<BE, 256, 0, stream>>>(src, dst, cursor, src_csr, nE);

    // --- layer 1: x (fp32) -> HWS -> AGG(bufB, fp16) ---
    k_gemm_mfma<<<BG, 256, 0, stream>>>(x, nullptr, Wt1, dis, bufA, nN);
    k_gather   <<<BGA, 256, 0, stream>>>(bufA, row_ptr, src_csr, dis, b1, bufB, nN);

    // --- layer 2: relu(bufB fp16) -> HWS -> AGG(bufB) ---
    k_gemm_mfma<<<BG, 256, 0, stream>>>(nullptr, bufB, Wt2, dis, bufA, nN);
    k_gather   <<<BGA, 256, 0, stream>>>(bufA, row_ptr, src_csr, dis, b2, bufB, nN);

    // --- layer 3: relu(bufB) -> d_out ---
    k_gemv   <<<BGV, 256, 0, stream>>>(bufB, W3, dis, hw3s, nN);
    k_gather3<<<BN, 256, 0, stream>>>(hw3s, row_ptr, src_csr, dis, b3,
                                      (float*)d_out, nN);
}

// Round 11
// 259.700 us; speedup vs baseline: 2.8122x; 1.0288x over previous
//
#include <hip/hip_runtime.h>
#include <hip/hip_fp16.h>

// ---------------------------------------------------------------------------
// 3-layer GCN, CSR-gather, fp16 dataflow + MFMA GEMM, fused pipeline:
//   gemm1:        HWS1 = half(dis * (x @ W1))            (MFMA 16x16x32 f16)
//   gather+gemm2: h1 = relu(dis*Σ HWS1 + b1) -> LDS -> HWS2 = half(dis*(h1@W2))
//   gather+gemv:  hw3s = dis * dot(relu(dis*Σ HWS2 + b2), W3)
//   gather3:      out = relu(dis*Σ hw3s + b3)
// Lessons: R4/R5 never force __launch_bounds__ min-waves (VGPR cap 256/w ->
// spills). R7/R8: gather is bytes-below-L2 bound (fp16 halves it); R10:
// multi-pass src-partitioning is worse (8 XCD x first-touch > random-hit).
// ---------------------------------------------------------------------------

typedef _Float16 v8h __attribute__((ext_vector_type(8)));
typedef float v4f __attribute__((ext_vector_type(4)));

// fused: edge count (blocks [0,BE)) + weight cast/transpose (blocks [BE,BE+64))
__global__ __launch_bounds__(256) void k_count_wcast(const int* __restrict__ dst,
                                                     int* __restrict__ cnt, int nE,
                                                     int BE,
                                                     const float* __restrict__ W1,
                                                     const float* __restrict__ W2,
                                                     __half* __restrict__ Wt1,
                                                     __half* __restrict__ Wt2) {
    int b = blockIdx.x;
    if (b < BE) {
        int e = b * 256 + threadIdx.x;
        if (e < nE) atomicAdd(&cnt[dst[e]], 1);
    } else {
        int i = (b - BE) * 256 + threadIdx.x;   // 0..16383
        int k = i >> 7, c = i & 127;
        Wt1[c * 128 + k] = __float2half(W1[i]);
        Wt2[c * 128 + k] = __float2half(W2[i]);
    }
}

// scan stage 1 + fused dis = rsqrt(cnt+1)
__global__ __launch_bounds__(256) void k_scan_blk(const int* __restrict__ cnt,
                                                  float* __restrict__ dis,
                                                  int* __restrict__ excl,
                                                  int* __restrict__ blk_sum, int nN) {
    __shared__ int sm[256];
    const int t = threadIdx.x;
    int i = blockIdx.x * 256 + t;
    int v = (i < nN) ? cnt[i] : 0;
    if (i < nN) dis[i] = rsqrtf((float)v + 1.0f);
    sm[t] = v;
    __syncthreads();
#pragma unroll
    for (int off = 1; off < 256; off <<= 1) {
        int x = (t >= off) ? sm[t - off] : 0;
        __syncthreads();
        sm[t] += x;
        __syncthreads();
    }
    if (i < nN) excl[i] = sm[t] - v;
    if (t == 255) blk_sum[blockIdx.x] = sm[255];
}

__global__ __launch_bounds__(256) void k_scan_top(int* __restrict__ blk_sum, int nB) {
    __shared__ int sm[256];
    const int t = threadIdx.x;
    int v = (t < nB) ? blk_sum[t] : 0;
    sm[t] = v;
    __syncthreads();
#pragma unroll
    for (int off = 1; off < 256; off <<= 1) {
        int x = (t >= off) ? sm[t - off] : 0;
        __syncthreads();
        sm[t] += x;
        __syncthreads();
    }
    if (t < nB) blk_sum[t] = sm[t] - v;
    if (t == 0) blk_sum[nB] = sm[255];
}

__global__ __launch_bounds__(256) void k_scan_add(const int* __restrict__ excl,
                                                  const int* __restrict__ blk_sum,
                                                  int* __restrict__ row_ptr,
                                                  int* __restrict__ cursor,
                                                  int nN, int nB) {
    int i = blockIdx.x * 256 + threadIdx.x;
    if (i < nN) {
        int v = excl[i] + blk_sum[i >> 8];
        row_ptr[i] = v;
        cursor[i] = v;
    }
    if (i == 0) row_ptr[nN] = blk_sum[nB];
}

__global__ __launch_bounds__(256) void k_bin(const int* __restrict__ src,
                                             const int* __restrict__ dst,
                                             int* __restrict__ cursor,
                                             int* __restrict__ src_csr, int nE) {
    int e = blockIdx.x * 256 + threadIdx.x;
    if (e >= nE) return;
    int s = src[e], d = dst[e];
    int pos = atomicAdd(&cursor[d], 1);
    src_csr[pos] = s;
}

// register-accumulated pull of one node row (32 lanes x 4 halves = 128 cols),
// fp32 acc; includes the self term HWS[g].
__device__ __forceinline__ float4 gather_row(const float2* __restrict__ Hv,
                                             const int* __restrict__ row_ptr,
                                             const int* __restrict__ src_csr,
                                             int g, int f4) {
    int beg = row_ptr[g], end = row_ptr[g + 1];
    float2 r0 = Hv[(size_t)g * 32 + f4];
    float2 lo = __half22float2(*(__half2*)&r0.x);
    float2 hi = __half22float2(*(__half2*)&r0.y);
    float4 acc = make_float4(lo.x, lo.y, hi.x, hi.y);
    int e = beg;
    for (; e + 8 <= end; e += 8) {
        int s[8];
#pragma unroll
        for (int j = 0; j < 8; ++j) s[j] = src_csr[e + j];
        float2 r[8];
#pragma unroll
        for (int j = 0; j < 8; ++j) r[j] = Hv[(size_t)s[j] * 32 + f4];
#pragma unroll
        for (int j = 0; j < 8; ++j) {
            float2 l2 = __half22float2(*(__half2*)&r[j].x);
            float2 h2 = __half22float2(*(__half2*)&r[j].y);
            acc.x += l2.x; acc.y += l2.y; acc.z += h2.x; acc.w += h2.y;
        }
    }
    if (e + 4 <= end) {
        int s[4];
#pragma unroll
        for (int j = 0; j < 4; ++j) s[j] = src_csr[e + j];
        float2 r[4];
#pragma unroll
        for (int j = 0; j < 4; ++j) r[j] = Hv[(size_t)s[j] * 32 + f4];
#pragma unroll
        for (int j = 0; j < 4; ++j) {
            float2 l2 = __half22float2(*(__half2*)&r[j].x);
            float2 h2 = __half22float2(*(__half2*)&r[j].y);
            acc.x += l2.x; acc.y += l2.y; acc.z += h2.x; acc.w += h2.y;
        }
        e += 4;
    }
    for (; e < end; ++e) {
        float2 r = Hv[(size_t)src_csr[e] * 32 + f4];
        float2 l2 = __half22float2(*(__half2*)&r.x);
        float2 h2 = __half22float2(*(__half2*)&r.y);
        acc.x += l2.x; acc.y += l2.y; acc.z += h2.x; acc.w += h2.y;
    }
    return acc;
}

// layer-1 MFMA GEMM: HWS1 = half( dis[row] * (x @ W1) ), x fp32 [nN x 128].
// 64 rows/block, LDS pitch 136 halves; Wt from global (L2-hot, broadcast).
__global__ __launch_bounds__(256) void k_gemm_mfma(const float* __restrict__ X32,
                                                   const __half* __restrict__ Wt,
                                                   const float* __restrict__ dis,
                                                   __half* __restrict__ HWS,
                                                   int nrows) {
    __shared__ __half xs[64 * 136];
    const int t = threadIdx.x;
    const int row0 = blockIdx.x * 64;

#pragma unroll
    for (int i = 0; i < 8; ++i) {
        int f = t + i * 256;
        int r = f >> 5, k4 = f & 31;
        int gr = row0 + r;
        float4 v = make_float4(0.f, 0.f, 0.f, 0.f);
        if (gr < nrows) v = ((const float4*)X32)[(size_t)gr * 32 + k4];
        __half2 h01 = __float22half2_rn(make_float2(v.x, v.y));
        __half2 h23 = __float22half2_rn(make_float2(v.z, v.w));
        float2 packed;
        *(__half2*)&packed.x = h01;
        *(__half2*)&packed.y = h23;
        *(float2*)&xs[r * 136 + k4 * 4] = packed;
    }
    __syncthreads();

    const int w = t >> 6;
    const int l = t & 63;
    const int mrow = l & 15;
    const int kq = l >> 4;

    v8h a[4];
#pragma unroll
    for (int kk = 0; kk < 4; ++kk)
        a[kk] = *(const v8h*)&xs[(w * 16 + mrow) * 136 + kk * 32 + kq * 8];

    v4f acc[8];
#pragma unroll
    for (int c = 0; c < 8; ++c) acc[c] = (v4f){0.f, 0.f, 0.f, 0.f};

#pragma unroll
    for (int kk = 0; kk < 4; ++kk) {
#pragma unroll
        for (int c = 0; c < 8; ++c) {
            v8h b = *(const v8h*)&Wt[(size_t)(c * 16 + mrow) * 128 + kk * 32 + kq * 8];
            acc[c] = __builtin_amdgcn_mfma_f32_16x16x32_f16(a[kk], b, acc[c], 0, 0, 0);
        }
    }

    float dn[4];
#pragma unroll
    for (int r = 0; r < 4; ++r) {
        int grow = row0 + w * 16 + kq * 4 + r;
        dn[r] = (grow < nrows) ? dis[grow] : 0.f;
    }
#pragma unroll
    for (int c = 0; c < 8; ++c) {
#pragma unroll
        for (int r = 0; r < 4; ++r) {
            int grow = row0 + w * 16 + kq * 4 + r;
            if (grow < nrows)
                HWS[(size_t)grow * 128 + c * 16 + mrow] =
                    __float2half(acc[c][r] * dn[r]);
        }
    }
}

// FUSED layer-1 gather + layer-2 GEMM:
//   phase 1: 8 half-waves x 8 nodes: h1 = relu(dis*Σ HWS1 + b1) -> LDS fp16
//   phase 2: MFMA h1 @ W2, epilogue HWS2 = half(dis * result)
__global__ __launch_bounds__(256) void k_gather_gemm(const __half* __restrict__ HWS1,
                                                     const int* __restrict__ row_ptr,
                                                     const int* __restrict__ src_csr,
                                                     const float* __restrict__ dis,
                                                     const float* __restrict__ bias,
                                                     const __half* __restrict__ Wt,
                                                     __half* __restrict__ HWS2,
                                                     int nN) {
    __shared__ __half xs[64 * 136];
    const int t = threadIdx.x;
    const int row0 = blockIdx.x * 64;
    const int hw_id = t >> 5;   // half-wave 0..7
    const int f4 = t & 31;
    const float2* Hv = (const float2*)HWS1;
    const float4 bv = ((const float4*)bias)[f4];

#pragma unroll 1
    for (int i = 0; i < 8; ++i) {
        int lr = i * 8 + hw_id;
        int g = row0 + lr;
        float4 h = make_float4(0.f, 0.f, 0.f, 0.f);
        if (g < nN) {
            float4 acc = gather_row(Hv, row_ptr, src_csr, g, f4);
            float dn = dis[g];
            h.x = fmaxf(acc.x * dn + bv.x, 0.f);
            h.y = fmaxf(acc.y * dn + bv.y, 0.f);
            h.z = fmaxf(acc.z * dn + bv.z, 0.f);
            h.w = fmaxf(acc.w * dn + bv.w, 0.f);
        }
        __half2 h01 = __float22half2_rn(make_float2(h.x, h.y));
        __half2 h23 = __float22half2_rn(make_float2(h.z, h.w));
        float2 packed;
        *(__half2*)&packed.x = h01;
        *(__half2*)&packed.y = h23;
        *(float2*)&xs[lr * 136 + f4 * 4] = packed;
    }
    __syncthreads();

    const int w = t >> 6;
    const int l = t & 63;
    const int mrow = l & 15;
    const int kq = l >> 4;

    v8h a[4];
#pragma unroll
    for (int kk = 0; kk < 4; ++kk)
        a[kk] = *(const v8h*)&xs[(w * 16 + mrow) * 136 + kk * 32 + kq * 8];

    v4f acc[8];
#pragma unroll
    for (int c = 0; c < 8; ++c) acc[c] = (v4f){0.f, 0.f, 0.f, 0.f};

#pragma unroll
    for (int kk = 0; kk < 4; ++kk) {
#pragma unroll
        for (int c = 0; c < 8; ++c) {
            v8h b = *(const v8h*)&Wt[(size_t)(c * 16 + mrow) * 128 + kk * 32 + kq * 8];
            acc[c] = __builtin_amdgcn_mfma_f32_16x16x32_f16(a[kk], b, acc[c], 0, 0, 0);
        }
    }

    float dn4[4];
#pragma unroll
    for (int r = 0; r < 4; ++r) {
        int grow = row0 + w * 16 + kq * 4 + r;
        dn4[r] = (grow < nN) ? dis[grow] : 0.f;
    }
#pragma unroll
    for (int c = 0; c < 8; ++c) {
#pragma unroll
        for (int r = 0; r < 4; ++r) {
            int grow = row0 + w * 16 + kq * 4 + r;
            if (grow < nN)
                HWS2[(size_t)grow * 128 + c * 16 + mrow] =
                    __float2half(acc[c][r] * dn4[r]);
        }
    }
}

// FUSED layer-2 gather + layer-3 gemv:
//   hw3s[g] = dis[g] * dot(relu(dis[g]*Σ HWS2 + b2), W3)
__global__ __launch_bounds__(256) void k_gather_gemv(const __half* __restrict__ HWS2,
                                                     const int* __restrict__ row_ptr,
                                                     const int* __restrict__ src_csr,
                                                     const float* __restrict__ dis,
                                                     const float* __restrict__ bias,
                                                     const float* __restrict__ W3,
                                                     float* __restrict__ hw3s, int nN) {
    int g = blockIdx.x * 8 + (threadIdx.x >> 5);
    if (g >= nN) return;
    int f4 = threadIdx.x & 31;
    float4 acc = gather_row((const float2*)HWS2, row_ptr, src_csr, g, f4);
    float dn = dis[g];
    float4 bv = ((const float4*)bias)[f4];
    float4 w  = ((const float4*)W3)[f4];
    float sum = fmaxf(acc.x * dn + bv.x, 0.f) * w.x
              + fmaxf(acc.y * dn + bv.y, 0.f) * w.y
              + fmaxf(acc.z * dn + bv.z, 0.f) * w.z
              + fmaxf(acc.w * dn + bv.w, 0.f) * w.w;
#pragma unroll
    for (int off = 16; off > 0; off >>= 1) sum += __shfl_down(sum, off, 32);
    if (f4 == 0) hw3s[g] = sum * dn;
}

// scalar pull-aggregation + final relu -> d_out
__global__ __launch_bounds__(256) void k_gather3(const float* __restrict__ hw3s,
                                                 const int* __restrict__ row_ptr,
                                                 const int* __restrict__ src_csr,
                                                 const float* __restrict__ dis,
                                                 const float* __restrict__ b3,
                                                 float* __restrict__ out, int nN) {
    int i = blockIdx.x * 256 + threadIdx.x;
    if (i >= nN) return;
    float acc = hw3s[i];
    int beg = row_ptr[i], end = row_ptr[i + 1];
    for (int e = beg; e < end; ++e) acc += hw3s[src_csr[e]];
    out[i] = fmaxf(acc * dis[i] + b3[0], 0.f);
}

extern "C" void kernel_launch(void* const* d_in, const int* in_sizes, int n_in,
                              void* d_out, int out_size, void* d_ws, size_t ws_size,
                              hipStream_t stream) {
    const float* x  = (const float*)d_in[0];
    const int*   ei = (const int*)d_in[1];
    const float* W1 = (const float*)d_in[2];
    const float* b1 = (const float*)d_in[3];
    const float* W2 = (const float*)d_in[4];
    const float* b2 = (const float*)d_in[5];
    const float* W3 = (const float*)d_in[6];
    const float* b3 = (const float*)d_in[7];

    const int nN = in_sizes[0] / 128;
    const int nE = in_sizes[1] / 2;
    const int* src = ei;
    const int* dst = ei + nE;

    const int nB = (nN + 255) / 256;   // scan blocks

    // workspace layout
    char* p = (char*)d_ws;
    int*    cnt      = (int*)p;           p += (size_t)nN * 4;
    int*    cursor   = (int*)p;           p += (size_t)nN * 4;
    int*    excl     = (int*)p;           p += (size_t)nN * 4;
    int*    blk_sum  = (int*)p;           p += (size_t)(nB + 1) * 4;
    int*    row_ptr  = (int*)p;           p += (size_t)(nN + 1) * 4;
    int*    src_csr  = (int*)p;           p += (size_t)nE * 4;
    float*  dis      = (float*)p;         p += (size_t)nN * 4;
    float*  hw3s     = (float*)p;         p += (size_t)nN * 4;
    p = (char*)(((uintptr_t)p + 255) & ~(uintptr_t)255);
    __half* Wt1      = (__half*)p;        p += (size_t)128 * 128 * 2;
    __half* Wt2      = (__half*)p;        p += (size_t)128 * 128 * 2;
    __half* bufA     = (__half*)p;        p += (size_t)nN * 128 * 2;  // HWS1
    p = (char*)(((uintptr_t)p + 255) & ~(uintptr_t)255);
    __half* bufB     = (__half*)p;        p += (size_t)nN * 128 * 2;  // HWS2

    const int BE  = (nE + 255) / 256;
    const int BN  = (nN + 255) / 256;
    const int BG  = (nN + 63) / 64;
    const int BGA = (nN + 7) / 8;

    // --- CSR build + norms + weight cast ---
    hipMemsetAsync(cnt, 0, (size_t)nN * sizeof(int), stream);
    k_count_wcast<<<BE + 64, 256, 0, stream>>>(dst, cnt, nE, BE, W1, W2, Wt1, Wt2);
    k_scan_blk<<<nB, 256, 0, stream>>>(cnt, dis, excl, blk_sum, nN);
    k_scan_top<<<1, 256, 0, stream>>>(blk_sum, nB);
    k_scan_add<<<nB, 256, 0, stream>>>(excl, blk_sum, row_ptr, cursor, nN, nB);
    k_bin     <<<BE, 256, 0, stream>>>(src, dst, cursor, src_csr, nE);

    // --- layer 1 GEMM: x -> HWS1 ---
    k_gemm_mfma<<<BG, 256, 0, stream>>>(x, Wt1, dis, bufA, nN);

    // --- fused layer-1 gather + layer-2 GEMM: HWS1 -> HWS2 ---
    k_gather_gemm<<<BG, 256, 0, stream>>>(bufA, row_ptr, src_csr, dis, b1, Wt2,
                                          bufB, nN);

    // --- fused layer-2 gather + layer-3 gemv: HWS2 -> hw3s ---
    k_gather_gemv<<<BGA, 256, 0, stream>>>(bufB, row_ptr, src_csr, dis, b2, W3,
                                           hw3s, nN);

    // --- layer-3 scalar gather -> d_out ---
    k_gather3<<<BN, 256, 0, stream>>>(hw3s, row_ptr, src_csr, dis, b3,
                                      (float*)d_out, nN);
}

// Round 12
// 247.991 us; speedup vs baseline: 2.9450x; 1.0472x over previous
//
#include <hip/hip_runtime.h>
#include <hip/hip_fp16.h>

// ---------------------------------------------------------------------------
// 3-layer GCN, CSR-gather, fp16 dataflow + MFMA GEMM, fused pipeline:
//   gemm1:        HWS1 = half(dis * (x @ W1))            (MFMA 16x16x32 f16)
//   gather+gemm2: h1 = relu(dis*Σ HWS1 + b1) -> LDS -> HWS2 = half(dis*(h1@W2))
//                 [512-thr blocks: 16 half-wave gather units + 8 MFMA waves]
//   gather+gemv:  hw3s = dis * dot(relu(dis*Σ HWS2 + b2), W3)
//   gather3:      out = relu(dis*Σ hw3s + b3)
// Lessons: R4/R5 never force __launch_bounds__ min-waves (VGPR cap 256/w ->
// spills). R7/R8: gather is bytes-below-L2 bound (fp16 halves it). R11:
// fusing gather into the 64-row GEMM grid (782 blocks) halved gather TLP ->
// 1.1TB/s; fix is more waves per block, not less fusion.
// ---------------------------------------------------------------------------

typedef _Float16 v8h __attribute__((ext_vector_type(8)));
typedef float v4f __attribute__((ext_vector_type(4)));

// fused: edge count (blocks [0,BE)) + weight cast/transpose (blocks [BE,BE+64))
__global__ __launch_bounds__(256) void k_count_wcast(const int* __restrict__ dst,
                                                     int* __restrict__ cnt, int nE,
                                                     int BE,
                                                     const float* __restrict__ W1,
                                                     const float* __restrict__ W2,
                                                     __half* __restrict__ Wt1,
                                                     __half* __restrict__ Wt2) {
    int b = blockIdx.x;
    if (b < BE) {
        int e = b * 256 + threadIdx.x;
        if (e < nE) atomicAdd(&cnt[dst[e]], 1);
    } else {
        int i = (b - BE) * 256 + threadIdx.x;   // 0..16383
        int k = i >> 7, c = i & 127;
        Wt1[c * 128 + k] = __float2half(W1[i]);
        Wt2[c * 128 + k] = __float2half(W2[i]);
    }
}

// scan stage 1 + fused dis = rsqrt(cnt+1)
__global__ __launch_bounds__(256) void k_scan_blk(const int* __restrict__ cnt,
                                                  float* __restrict__ dis,
                                                  int* __restrict__ excl,
                                                  int* __restrict__ blk_sum, int nN) {
    __shared__ int sm[256];
    const int t = threadIdx.x;
    int i = blockIdx.x * 256 + t;
    int v = (i < nN) ? cnt[i] : 0;
    if (i < nN) dis[i] = rsqrtf((float)v + 1.0f);
    sm[t] = v;
    __syncthreads();
#pragma unroll
    for (int off = 1; off < 256; off <<= 1) {
        int x = (t >= off) ? sm[t - off] : 0;
        __syncthreads();
        sm[t] += x;
        __syncthreads();
    }
    if (i < nN) excl[i] = sm[t] - v;
    if (t == 255) blk_sum[blockIdx.x] = sm[255];
}

__global__ __launch_bounds__(256) void k_scan_top(int* __restrict__ blk_sum, int nB) {
    __shared__ int sm[256];
    const int t = threadIdx.x;
    int v = (t < nB) ? blk_sum[t] : 0;
    sm[t] = v;
    __syncthreads();
#pragma unroll
    for (int off = 1; off < 256; off <<= 1) {
        int x = (t >= off) ? sm[t - off] : 0;
        __syncthreads();
        sm[t] += x;
        __syncthreads();
    }
    if (t < nB) blk_sum[t] = sm[t] - v;
    if (t == 0) blk_sum[nB] = sm[255];
}

__global__ __launch_bounds__(256) void k_scan_add(const int* __restrict__ excl,
                                                  const int* __restrict__ blk_sum,
                                                  int* __restrict__ row_ptr,
                                                  int* __restrict__ cursor,
                                                  int nN, int nB) {
    int i = blockIdx.x * 256 + threadIdx.x;
    if (i < nN) {
        int v = excl[i] + blk_sum[i >> 8];
        row_ptr[i] = v;
        cursor[i] = v;
    }
    if (i == 0) row_ptr[nN] = blk_sum[nB];
}

__global__ __launch_bounds__(256) void k_bin(const int* __restrict__ src,
                                             const int* __restrict__ dst,
                                             int* __restrict__ cursor,
                                             int* __restrict__ src_csr, int nE) {
    int e = blockIdx.x * 256 + threadIdx.x;
    if (e >= nE) return;
    int s = src[e], d = dst[e];
    int pos = atomicAdd(&cursor[d], 1);
    src_csr[pos] = s;
}

// register-accumulated pull of one node row (32 lanes x 4 halves = 128 cols),
// fp32 acc; includes the self term HWS[g].
__device__ __forceinline__ float4 gather_row(const float2* __restrict__ Hv,
                                             const int* __restrict__ row_ptr,
                                             const int* __restrict__ src_csr,
                                             int g, int f4) {
    int beg = row_ptr[g], end = row_ptr[g + 1];
    float2 r0 = Hv[(size_t)g * 32 + f4];
    float2 lo = __half22float2(*(__half2*)&r0.x);
    float2 hi = __half22float2(*(__half2*)&r0.y);
    float4 acc = make_float4(lo.x, lo.y, hi.x, hi.y);
    int e = beg;
    for (; e + 8 <= end; e += 8) {
        int s[8];
#pragma unroll
        for (int j = 0; j < 8; ++j) s[j] = src_csr[e + j];
        float2 r[8];
#pragma unroll
        for (int j = 0; j < 8; ++j) r[j] = Hv[(size_t)s[j] * 32 + f4];
#pragma unroll
        for (int j = 0; j < 8; ++j) {
            float2 l2 = __half22float2(*(__half2*)&r[j].x);
            float2 h2 = __half22float2(*(__half2*)&r[j].y);
            acc.x += l2.x; acc.y += l2.y; acc.z += h2.x; acc.w += h2.y;
        }
    }
    if (e + 4 <= end) {
        int s[4];
#pragma unroll
        for (int j = 0; j < 4; ++j) s[j] = src_csr[e + j];
        float2 r[4];
#pragma unroll
        for (int j = 0; j < 4; ++j) r[j] = Hv[(size_t)s[j] * 32 + f4];
#pragma unroll
        for (int j = 0; j < 4; ++j) {
            float2 l2 = __half22float2(*(__half2*)&r[j].x);
            float2 h2 = __half22float2(*(__half2*)&r[j].y);
            acc.x += l2.x; acc.y += l2.y; acc.z += h2.x; acc.w += h2.y;
        }
        e += 4;
    }
    for (; e < end; ++e) {
        float2 r = Hv[(size_t)src_csr[e] * 32 + f4];
        float2 l2 = __half22float2(*(__half2*)&r.x);
        float2 h2 = __half22float2(*(__half2*)&r.y);
        acc.x += l2.x; acc.y += l2.y; acc.z += h2.x; acc.w += h2.y;
    }
    return acc;
}

// layer-1 MFMA GEMM: HWS1 = half( dis[row] * (x @ W1) ), x fp32 [nN x 128].
// 64 rows/block, LDS pitch 136 halves; Wt from global (L2-hot, broadcast).
__global__ __launch_bounds__(256) void k_gemm_mfma(const float* __restrict__ X32,
                                                   const __half* __restrict__ Wt,
                                                   const float* __restrict__ dis,
                                                   __half* __restrict__ HWS,
                                                   int nrows) {
    __shared__ __half xs[64 * 136];
    const int t = threadIdx.x;
    const int row0 = blockIdx.x * 64;

#pragma unroll
    for (int i = 0; i < 8; ++i) {
        int f = t + i * 256;
        int r = f >> 5, k4 = f & 31;
        int gr = row0 + r;
        float4 v = make_float4(0.f, 0.f, 0.f, 0.f);
        if (gr < nrows) v = ((const float4*)X32)[(size_t)gr * 32 + k4];
        __half2 h01 = __float22half2_rn(make_float2(v.x, v.y));
        __half2 h23 = __float22half2_rn(make_float2(v.z, v.w));
        float2 packed;
        *(__half2*)&packed.x = h01;
        *(__half2*)&packed.y = h23;
        *(float2*)&xs[r * 136 + k4 * 4] = packed;
    }
    __syncthreads();

    const int w = t >> 6;
    const int l = t & 63;
    const int mrow = l & 15;
    const int kq = l >> 4;

    v8h a[4];
#pragma unroll
    for (int kk = 0; kk < 4; ++kk)
        a[kk] = *(const v8h*)&xs[(w * 16 + mrow) * 136 + kk * 32 + kq * 8];

    v4f acc[8];
#pragma unroll
    for (int c = 0; c < 8; ++c) acc[c] = (v4f){0.f, 0.f, 0.f, 0.f};

#pragma unroll
    for (int kk = 0; kk < 4; ++kk) {
#pragma unroll
        for (int c = 0; c < 8; ++c) {
            v8h b = *(const v8h*)&Wt[(size_t)(c * 16 + mrow) * 128 + kk * 32 + kq * 8];
            acc[c] = __builtin_amdgcn_mfma_f32_16x16x32_f16(a[kk], b, acc[c], 0, 0, 0);
        }
    }

    float dn[4];
#pragma unroll
    for (int r = 0; r < 4; ++r) {
        int grow = row0 + w * 16 + kq * 4 + r;
        dn[r] = (grow < nrows) ? dis[grow] : 0.f;
    }
#pragma unroll
    for (int c = 0; c < 8; ++c) {
#pragma unroll
        for (int r = 0; r < 4; ++r) {
            int grow = row0 + w * 16 + kq * 4 + r;
            if (grow < nrows)
                HWS[(size_t)grow * 128 + c * 16 + mrow] =
                    __float2half(acc[c][r] * dn[r]);
        }
    }
}

// FUSED layer-1 gather + layer-2 GEMM, 512 threads (R11 fix: 2x waves for
// the latency-bound gather phase):
//   phase 1: 16 half-waves x 4 nodes: h1 = relu(dis*Σ HWS1 + b1) -> LDS fp16
//   phase 2: 8 MFMA waves; wave w owns rows (w&3)*16..+16, cols (w>>2)*64..+64
__global__ __launch_bounds__(512) void k_gather_gemm(const __half* __restrict__ HWS1,
                                                     const int* __restrict__ row_ptr,
                                                     const int* __restrict__ src_csr,
                                                     const float* __restrict__ dis,
                                                     const float* __restrict__ bias,
                                                     const __half* __restrict__ Wt,
                                                     __half* __restrict__ HWS2,
                                                     int nN) {
    __shared__ __half xs[64 * 136];
    const int t = threadIdx.x;
    const int row0 = blockIdx.x * 64;
    const int hw_id = t >> 5;   // half-wave 0..15
    const int f4 = t & 31;
    const float2* Hv = (const float2*)HWS1;
    const float4 bv = ((const float4*)bias)[f4];

#pragma unroll 1
    for (int i = 0; i < 4; ++i) {
        int lr = i * 16 + hw_id;
        int g = row0 + lr;
        float4 h = make_float4(0.f, 0.f, 0.f, 0.f);
        if (g < nN) {
            float4 acc = gather_row(Hv, row_ptr, src_csr, g, f4);
            float dn = dis[g];
            h.x = fmaxf(acc.x * dn + bv.x, 0.f);
            h.y = fmaxf(acc.y * dn + bv.y, 0.f);
            h.z = fmaxf(acc.z * dn + bv.z, 0.f);
            h.w = fmaxf(acc.w * dn + bv.w, 0.f);
        }
        __half2 h01 = __float22half2_rn(make_float2(h.x, h.y));
        __half2 h23 = __float22half2_rn(make_float2(h.z, h.w));
        float2 packed;
        *(__half2*)&packed.x = h01;
        *(__half2*)&packed.y = h23;
        *(float2*)&xs[lr * 136 + f4 * 4] = packed;
    }
    __syncthreads();

    const int w = t >> 6;        // wave 0..7
    const int l = t & 63;
    const int mrow = l & 15;
    const int kq = l >> 4;
    const int rgrp = (w & 3) * 16;   // row group
    const int cgrp = (w >> 2) * 4;   // col-tile group (4 tiles of 16)

    v8h a[4];
#pragma unroll
    for (int kk = 0; kk < 4; ++kk)
        a[kk] = *(const v8h*)&xs[(rgrp + mrow) * 136 + kk * 32 + kq * 8];

    v4f acc[4];
#pragma unroll
    for (int c = 0; c < 4; ++c) acc[c] = (v4f){0.f, 0.f, 0.f, 0.f};

#pragma unroll
    for (int kk = 0; kk < 4; ++kk) {
#pragma unroll
        for (int c = 0; c < 4; ++c) {
            v8h b = *(const v8h*)&Wt[(size_t)((cgrp + c) * 16 + mrow) * 128 + kk * 32 + kq * 8];
            acc[c] = __builtin_amdgcn_mfma_f32_16x16x32_f16(a[kk], b, acc[c], 0, 0, 0);
        }
    }

    float dn4[4];
#pragma unroll
    for (int r = 0; r < 4; ++r) {
        int grow = row0 + rgrp + kq * 4 + r;
        dn4[r] = (grow < nN) ? dis[grow] : 0.f;
    }
#pragma unroll
    for (int c = 0; c < 4; ++c) {
#pragma unroll
        for (int r = 0; r < 4; ++r) {
            int grow = row0 + rgrp + kq * 4 + r;
            if (grow < nN)
                HWS2[(size_t)grow * 128 + (cgrp + c) * 16 + mrow] =
                    __float2half(acc[c][r] * dn4[r]);
        }
    }
}

// FUSED layer-2 gather + layer-3 gemv:
//   hw3s[g] = dis[g] * dot(relu(dis[g]*Σ HWS2 + b2), W3)
__global__ __launch_bounds__(256) void k_gather_gemv(const __half* __restrict__ HWS2,
                                                     const int* __restrict__ row_ptr,
                                                     const int* __restrict__ src_csr,
                                                     const float* __restrict__ dis,
                                                     const float* __restrict__ bias,
                                                     const float* __restrict__ W3,
                                                     float* __restrict__ hw3s, int nN) {
    int g = blockIdx.x * 8 + (threadIdx.x >> 5);
    if (g >= nN) return;
    int f4 = threadIdx.x & 31;
    float4 acc = gather_row((const float2*)HWS2, row_ptr, src_csr, g, f4);
    float dn = dis[g];
    float4 bv = ((const float4*)bias)[f4];
    float4 w  = ((const float4*)W3)[f4];
    float sum = fmaxf(acc.x * dn + bv.x, 0.f) * w.x
              + fmaxf(acc.y * dn + bv.y, 0.f) * w.y
              + fmaxf(acc.z * dn + bv.z, 0.f) * w.z
              + fmaxf(acc.w * dn + bv.w, 0.f) * w.w;
#pragma unroll
    for (int off = 16; off > 0; off >>= 1) sum += __shfl_down(sum, off, 32);
    if (f4 == 0) hw3s[g] = sum * dn;
}

// scalar pull-aggregation + final relu -> d_out
__global__ __launch_bounds__(256) void k_gather3(const float* __restrict__ hw3s,
                                                 const int* __restrict__ row_ptr,
                                                 const int* __restrict__ src_csr,
                                                 const float* __restrict__ dis,
                                                 const float* __restrict__ b3,
                                                 float* __restrict__ out, int nN) {
    int i = blockIdx.x * 256 + threadIdx.x;
    if (i >= nN) return;
    float acc = hw3s[i];
    int beg = row_ptr[i], end = row_ptr[i + 1];
    for (int e = beg; e < end; ++e) acc += hw3s[src_csr[e]];
    out[i] = fmaxf(acc * dis[i] + b3[0], 0.f);
}

extern "C" void kernel_launch(void* const* d_in, const int* in_sizes, int n_in,
                              void* d_out, int out_size, void* d_ws, size_t ws_size,
                              hipStream_t stream) {
    const float* x  = (const float*)d_in[0];
    const int*   ei = (const int*)d_in[1];
    const float* W1 = (const float*)d_in[2];
    const float* b1 = (const float*)d_in[3];
    const float* W2 = (const float*)d_in[4];
    const float* b2 = (const float*)d_in[5];
    const float* W3 = (const float*)d_in[6];
    const float* b3 = (const float*)d_in[7];

    const int nN = in_sizes[0] / 128;
    const int nE = in_sizes[1] / 2;
    const int* src = ei;
    const int* dst = ei + nE;

    const int nB = (nN + 255) / 256;   // scan blocks

    // workspace layout
    char* p = (char*)d_ws;
    int*    cnt      = (int*)p;           p += (size_t)nN * 4;
    int*    cursor   = (int*)p;           p += (size_t)nN * 4;
    int*    excl     = (int*)p;           p += (size_t)nN * 4;
    int*    blk_sum  = (int*)p;           p += (size_t)(nB + 1) * 4;
    int*    row_ptr  = (int*)p;           p += (size_t)(nN + 1) * 4;
    int*    src_csr  = (int*)p;           p += (size_t)nE * 4;
    float*  dis      = (float*)p;         p += (size_t)nN * 4;
    float*  hw3s     = (float*)p;         p += (size_t)nN * 4;
    p = (char*)(((uintptr_t)p + 255) & ~(uintptr_t)255);
    __half* Wt1      = (__half*)p;        p += (size_t)128 * 128 * 2;
    __half* Wt2      = (__half*)p;        p += (size_t)128 * 128 * 2;
    __half* bufA     = (__half*)p;        p += (size_t)nN * 128 * 2;  // HWS1
    p = (char*)(((uintptr_t)p + 255) & ~(uintptr_t)255);
    __half* bufB     = (__half*)p;        p += (size_t)nN * 128 * 2;  // HWS2

    const int BE  = (nE + 255) / 256;
    const int BN  = (nN + 255) / 256;
    const int BG  = (nN + 63) / 64;
    const int BGA = (nN + 7) / 8;

    // --- CSR build + norms + weight cast ---
    hipMemsetAsync(cnt, 0, (size_t)nN * sizeof(int), stream);
    k_count_wcast<<<BE + 64, 256, 0, stream>>>(dst, cnt, nE, BE, W1, W2, Wt1, Wt2);
    k_scan_blk<<<nB, 256, 0, stream>>>(cnt, dis, excl, blk_sum, nN);
    k_scan_top<<<1, 256, 0, stream>>>(blk_sum, nB);
    k_scan_add<<<nB, 256, 0, stream>>>(excl, blk_sum, row_ptr, cursor, nN, nB);
    k_bin     <<<BE, 256, 0, stream>>>(src, dst, cursor, src_csr, nE);

    // --- layer 1 GEMM: x -> HWS1 ---
    k_gemm_mfma<<<BG, 256, 0, stream>>>(x, Wt1, dis, bufA, nN);

    // --- fused layer-1 gather + layer-2 GEMM: HWS1 -> HWS2 (512 thr) ---
    k_gather_gemm<<<BG, 512, 0, stream>>>(bufA, row_ptr, src_csr, dis, b1, Wt2,
                                          bufB, nN);

    // --- fused layer-2 gather + layer-3 gemv: HWS2 -> hw3s ---
    k_gather_gemv<<<BGA, 256, 0, stream>>>(bufB, row_ptr, src_csr, dis, b2, W3,
                                           hw3s, nN);

    // --- layer-3 scalar gather -> d_out ---
    k_gather3<<<BN, 256, 0, stream>>>(hw3s, row_ptr, src_csr, dis, b3,
                                      (float*)d_out, nN);
}